// Round 13
// baseline (651.546 us; speedup 1.0000x reference)
//
#include <hip/hip_runtime.h>
#include <math.h>

#define BB 4
#define NN 2048
#define EE 2048

typedef __attribute__((ext_vector_type(8))) unsigned short ushort8;
typedef __attribute__((ext_vector_type(8))) __bf16 bf16x8;
typedef __attribute__((ext_vector_type(4))) float f32x4;

// ---------- helpers ----------
__device__ __forceinline__ unsigned short f2bf(float f) {
  unsigned int u = __float_as_uint(f);
  u = u + 0x7fffu + ((u >> 16) & 1u);   // RNE; inputs are finite
  return (unsigned short)(u >> 16);
}
__device__ __forceinline__ float bf2f(unsigned short h) {
  return __uint_as_float((unsigned)h << 16);
}

__device__ __forceinline__ void gload16(const void* g, void* l) {
  __builtin_amdgcn_global_load_lds(
      (__attribute__((address_space(1))) void*)g,
      (__attribute__((address_space(3))) void*)l, 16, 0, 0);
}

#define BARRIER() __builtin_amdgcn_s_barrier()
#define WAIT_VM(N) asm volatile("s_waitcnt vmcnt(" #N ")")

// ---------- fp32 -> bf16 conversion (vectorized) ----------
__global__ __launch_bounds__(256) void k_f32_to_bf16(const float* __restrict__ in,
                                                     unsigned short* __restrict__ out) {
  size_t i = (size_t)blockIdx.x * 256 + threadIdx.x;   // 8 elems each
  const float4* ip = (const float4*)in;
  float4 a = ip[i * 2];
  float4 b = ip[i * 2 + 1];
  ushort8 o;
  o[0] = f2bf(a.x); o[1] = f2bf(a.y); o[2] = f2bf(a.z); o[3] = f2bf(a.w);
  o[4] = f2bf(b.x); o[5] = f2bf(b.y); o[6] = f2bf(b.z); o[7] = f2bf(b.w);
  *((ushort8*)out + i) = o;
}

// ---------- fused q/k/v conversion, one dispatch (z selects tensor) ----------
__global__ __launch_bounds__(256) void k_conv3(const float* __restrict__ s0,
                                               const float* __restrict__ s1,
                                               const float* __restrict__ s2,
                                               unsigned short* __restrict__ d0,
                                               unsigned short* __restrict__ d1,
                                               unsigned short* __restrict__ d2) {
  const float* in; unsigned short* out;
  if (blockIdx.z == 0) { in = s0; out = d0; }
  else if (blockIdx.z == 1) { in = s1; out = d1; }
  else { in = s2; out = d2; }
  size_t i = (size_t)blockIdx.x * 256 + threadIdx.x;
  const float4* ip = (const float4*)in;
  float4 a = ip[i * 2];
  float4 b = ip[i * 2 + 1];
  ushort8 o;
  o[0] = f2bf(a.x); o[1] = f2bf(a.y); o[2] = f2bf(a.z); o[3] = f2bf(a.w);
  o[4] = f2bf(b.x); o[5] = f2bf(b.y); o[6] = f2bf(b.z); o[7] = f2bf(b.w);
  *((ushort8*)out + i) = o;
}

// ---------- fused fp32 read -> bf16 transposed write, 3 weights in one dispatch ----------
__global__ __launch_bounds__(256) void k_trf2b3(const float* __restrict__ s0,
                                                const float* __restrict__ s1,
                                                const float* __restrict__ s2,
                                                unsigned short* __restrict__ d0,
                                                unsigned short* __restrict__ d1,
                                                unsigned short* __restrict__ d2) {
  __shared__ __attribute__((aligned(16))) unsigned short tile[64][72];
  const float* in; unsigned short* out;
  if (blockIdx.z == 0) { in = s0; out = d0; }
  else if (blockIdx.z == 1) { in = s1; out = d1; }
  else { in = s2; out = d2; }
  const long eb = (long)blockIdx.x * 64;
  const long nb = (long)blockIdx.y * 64;
  const int t = threadIdx.x;
  const int r = t >> 3;
  const int c = (t & 7) * 8;

  const float* p0 = in + (nb + r) * (long)EE + eb + c;
  const float* p1 = in + (nb + 32 + r) * (long)EE + eb + c;
  float4 a0 = *(const float4*)p0, a1 = *(const float4*)(p0 + 4);
  float4 b0 = *(const float4*)p1, b1 = *(const float4*)(p1 + 4);
  unsigned short* t0 = &tile[r][c];
  unsigned short* t1 = &tile[r + 32][c];
  t0[0] = f2bf(a0.x); t0[1] = f2bf(a0.y); t0[2] = f2bf(a0.z); t0[3] = f2bf(a0.w);
  t0[4] = f2bf(a1.x); t0[5] = f2bf(a1.y); t0[6] = f2bf(a1.z); t0[7] = f2bf(a1.w);
  t1[0] = f2bf(b0.x); t1[1] = f2bf(b0.y); t1[2] = f2bf(b0.z); t1[3] = f2bf(b0.w);
  t1[4] = f2bf(b1.x); t1[5] = f2bf(b1.y); t1[6] = f2bf(b1.z); t1[7] = f2bf(b1.w);
  __syncthreads();
  ushort8 o0, o1;
#pragma unroll
  for (int j = 0; j < 8; j++) { o0[j] = tile[c + j][r]; o1[j] = tile[c + j][r + 32]; }
  *(ushort8*)(out + (eb + r) * (long)NN + nb + c) = o0;
  *(ushort8*)(out + (eb + r + 32) * (long)NN + nb + c) = o1;
}

// ---------- bf16 transpose [R,C] -> [C,R] per batch z ----------
__global__ __launch_bounds__(256) void k_transpose(const unsigned short* __restrict__ in,
                                                   unsigned short* __restrict__ out) {
  __shared__ __attribute__((aligned(16))) unsigned short tile[64][72];
  const long z = blockIdx.z;
  const long eb = (long)blockIdx.x * 64;
  const long nb = (long)blockIdx.y * 64;
  const unsigned short* ip = in + z * (long)NN * EE;
  unsigned short* op = out + z * (long)NN * EE;
  const int t = threadIdx.x;
  const int r = t >> 3;
  const int c = (t & 7) * 8;

  ushort8 u0 = *(const ushort8*)(ip + (nb + r) * EE + eb + c);
  ushort8 u1 = *(const ushort8*)(ip + (nb + 32 + r) * EE + eb + c);
  *(ushort8*)&tile[r][c] = u0;
  *(ushort8*)&tile[r + 32][c] = u1;
  __syncthreads();
  ushort8 o0, o1;
#pragma unroll
  for (int j = 0; j < 8; j++) { o0[j] = tile[c + j][r]; o1[j] = tile[c + j][r + 32]; }
  *(ushort8*)(op + (eb + r) * NN + nb + c) = o0;
  *(ushort8*)(op + (eb + r + 32) * NN + nb + c) = o1;
}

// ---------- bias precompute (general-bias; zeros in this input set) ----------
__global__ __launch_bounds__(256) void k_vecw(const float* __restrict__ Wq,
                                              const float* __restrict__ Wk,
                                              const float* __restrict__ bq,
                                              const float* __restrict__ bk,
                                              float* __restrict__ u,
                                              float* __restrict__ w2b,
                                              float* __restrict__ t4) {
  const int e = blockIdx.x * 256 + threadIdx.x;
  const int tt0 = blockIdx.y * 64;
  float su = 0.f, sw = 0.f;
#pragma unroll 4
  for (int i = 0; i < 64; i++) {
    int tt = tt0 + i;
    su += Wq[(long)tt * EE + e] * bk[tt];
    sw += Wk[(long)tt * EE + e] * bq[tt];
  }
  atomicAdd(&u[e], su);
  atomicAdd(&w2b[e], sw);
  if (blockIdx.x == 0 && threadIdx.x < 64) {
    int lane = threadIdx.x;
    float p = bq[tt0 + lane] * bk[tt0 + lane];
    for (int off = 32; off >= 1; off >>= 1) p += __shfl_down(p, off);
    if (lane == 0) atomicAdd(t4, p);
  }
}

__global__ __launch_bounds__(256) void k_cvec(const float* __restrict__ Wo,
                                              const float* __restrict__ bv,
                                              const float* __restrict__ bo,
                                              float* __restrict__ cv) {
  int row = blockIdx.x * 4 + (threadIdx.x >> 6);
  int lane = threadIdx.x & 63;
  float s = 0.f;
  for (int j = lane; j < EE; j += 64) s += Wo[(long)row * EE + j] * bv[j];
  for (int off = 32; off >= 1; off >>= 1) s += __shfl_down(s, off);
  if (lane == 0) cv[row] = s + bo[row];
}

__global__ __launch_bounds__(256) void k_rowterm(const unsigned short* __restrict__ qb,
                                                 const float* __restrict__ u,
                                                 const float* __restrict__ t4,
                                                 float* __restrict__ rt) {
  long row = (long)blockIdx.x * 4 + (threadIdx.x >> 6);
  int lane = threadIdx.x & 63;
  const unsigned short* qr = qb + row * EE;
  float s = 0.f;
#pragma unroll
  for (int it = 0; it < 4; ++it) {
    int e0 = it * 512 + lane * 8;
    ushort8 qv = *(const ushort8*)(qr + e0);
#pragma unroll
    for (int j = 0; j < 8; j++) s += bf2f(qv[j]) * u[e0 + j];
  }
  for (int off = 32; off >= 1; off >>= 1) s += __shfl_down(s, off);
  if (lane == 0) rt[row] = s + *t4;
}

// ---------- 128x128-tile GEMM for the z=2 weight precompute (512 wg, proven) ----------
__global__ __launch_bounds__(512, 4) void k_gemm128(
    const unsigned short* __restrict__ A, long lda, long sA,
    const unsigned short* __restrict__ Bm, long ldb, long sB,
    unsigned short* __restrict__ Co, long ldc, long sC, int K) {
  __shared__ __attribute__((aligned(16))) unsigned short As[2 * 8192];
  __shared__ __attribute__((aligned(16))) unsigned short Bs[2 * 8192];
  const int gx = gridDim.x, gy = gridDim.y;
  int lin = (int)blockIdx.x + gx * ((int)blockIdx.y + gy * (int)blockIdx.z);
  int nwg = gx * gy * (int)gridDim.z;
  int chunk = nwg >> 3;
  int sw = (lin & 7) * chunk + (lin >> 3);
  int bz = sw / (gx * gy); int rem = sw - bz * (gx * gy);
  int by = rem / gx; int bx = rem - by * gx;

  const long m0 = (long)by * 128;
  const long n0 = (long)bx * 128;
  const unsigned short* Ab = A + (long)bz * sA;
  const unsigned short* Bb = Bm + (long)bz * sB;
  const int t = threadIdx.x;
  const int lane = t & 63;
  const int w = t >> 6;
  const int wm = w >> 2, wn = w & 3;

  const int srow = t >> 3;
  const int scol = (((t & 7) * 16) ^ (((t >> 5) & 1) << 5)) >> 1;
  const unsigned short* Ga = Ab + (m0 + srow) * lda + scol;
  const unsigned short* Gb = Bb + (n0 + srow) * ldb + scol;
  const int ldst = t * 8;

#define STAGE(buf, tile) do { \
    const unsigned short* ga_ = Ga + (long)(tile) * 64; \
    const unsigned short* gb_ = Gb + (long)(tile) * 64; \
    unsigned short* la_ = As + (buf) * 8192 + ldst; \
    unsigned short* lb_ = Bs + (buf) * 8192 + ldst; \
    gload16(ga_, la_); gload16(ga_ + 64 * lda, la_ + 4096); \
    gload16(gb_, lb_); gload16(gb_ + 64 * ldb, lb_ + 4096); \
  } while (0)

  const int r = lane & 15;
  const int q = lane >> 4;
  const int rb2 = ((r * 128 + q * 16) ^ ((r & 4) << 3)) >> 1;
  const int aBase = wm * 4096 + rb2;
  const int bBase = wn * 2048 + rb2;

  f32x4 acc[4][2] = {};
  bf16x8 a[4][2], b[2][2];
  const int J = K >> 6;
  STAGE(0, 0);
  WAIT_VM(0);
  BARRIER();
  for (int j = 0; j < J; ++j) {
    const int c = j & 1;
    const unsigned short* Ac = As + c * 8192;
    const unsigned short* Bc = Bs + c * 8192;
#pragma unroll
    for (int mi = 0; mi < 4; mi++)
#pragma unroll
      for (int kk = 0; kk < 2; kk++)
        a[mi][kk] = *(const bf16x8*)(Ac + aBase + mi * 1024 + kk * 32);
#pragma unroll
    for (int ni = 0; ni < 2; ni++)
#pragma unroll
      for (int kk = 0; kk < 2; kk++)
        b[ni][kk] = *(const bf16x8*)(Bc + bBase + ni * 1024 + kk * 32);
    if (j + 1 < J) STAGE(c ^ 1, j + 1);
    __builtin_amdgcn_s_setprio(1);
#pragma unroll
    for (int mi = 0; mi < 4; mi++)
#pragma unroll
      for (int ni = 0; ni < 2; ni++)
#pragma unroll
        for (int kk = 0; kk < 2; kk++)
          acc[mi][ni] = __builtin_amdgcn_mfma_f32_16x16x32_bf16(
              a[mi][kk], b[ni][kk], acc[mi][ni], 0, 0, 0);
    __builtin_amdgcn_s_setprio(0);
    WAIT_VM(0);
    BARRIER();
  }
#undef STAGE
  const int cr0 = wm * 64 + (q << 2);
  const int cc0 = wn * 32 + r;
#pragma unroll
  for (int mi = 0; mi < 4; mi++)
#pragma unroll
    for (int rr = 0; rr < 4; rr++) {
      long row = m0 + cr0 + mi * 16 + rr;
#pragma unroll
      for (int ni = 0; ni < 2; ni++)
        Co[(long)bz * sC + row * ldc + n0 + cc0 + ni * 16] = f2bf(acc[mi][ni][rr]);
    }
}

// ---------- m97-exact 128x128 GEMM: 256 thr / 4 waves, BK=32, 16KB single-buffer LDS ----------
// Linear LDS [128][32] bf16; global_load_lds w16; 2 __syncthreads per K-step; builtin MFMA
// (acc in AGPRs). ~164 VGPR + 64 AGPR -> 3 blocks/CU; cross-block overlap hides barrier drain
// (m97/m103: 874-912 TF measured). Per wave: 64x64 output, acc[4][4].
// EPI 0: bf16 out (+bias[col])   EPI 1: scores -> bf16 compact + fp32 edge-dot
// EPI 2: f32 out + bias[col]
template <int EPI>
__global__ __launch_bounds__(256) void k_gemm97(
    const unsigned short* __restrict__ A, long lda, long sA,
    const unsigned short* __restrict__ Bm, long ldb, long sB,
    void* __restrict__ Cv, long ldc, long sC, int K,
    const float* __restrict__ bias,
    const int* __restrict__ mask, long sMask,
    const float* __restrict__ rt, float scale,
    const float* __restrict__ We, float* __restrict__ edot) {
  __shared__ __attribute__((aligned(16))) unsigned short As[128 * 32];
  __shared__ __attribute__((aligned(16))) unsigned short Bs[128 * 32];

  // bijective XCD-chunk swizzle (all grids multiples of 8)
  const int gx = gridDim.x, gy = gridDim.y;
  int lin = (int)blockIdx.x + gx * ((int)blockIdx.y + gy * (int)blockIdx.z);
  int nwg = gx * gy * (int)gridDim.z;
  int chunk = nwg >> 3;
  int sw = (lin & 7) * chunk + (lin >> 3);
  int bz = sw / (gx * gy); int rem = sw - bz * (gx * gy);
  int by = rem / gx; int bx = rem - by * gx;

  const long m0 = (long)by * 128;
  const long n0 = (long)bx * 128;
  const unsigned short* Ab = A + (long)bz * sA;
  const unsigned short* Bb = Bm + (long)bz * sB;

  const int t = threadIdx.x;
  const int lane = t & 63;
  const int w = t >> 6;
  const int wr = (w >> 1) * 64;
  const int wc = (w & 1) * 64;

  const int sr = t >> 2;          // 0..63
  const int sc = (t & 3) * 8;     // 0,8,16,24
  const unsigned short* ga0 = Ab + (m0 + sr) * lda + sc;
  const unsigned short* ga1 = ga0 + 64 * lda;
  const unsigned short* gb0 = Bb + (n0 + sr) * ldb + sc;
  const unsigned short* gb1 = gb0 + 64 * ldb;
  unsigned short* la0 = As + sr * 32 + sc;   // == t*16 bytes, wave-linear
  unsigned short* la1 = la0 + 64 * 32;
  unsigned short* lb0 = Bs + sr * 32 + sc;
  unsigned short* lb1 = lb0 + 64 * 32;

  f32x4 acc[4][4] = {};
  const int arow = wr + (lane & 15);
  const int brow = wc + (lane & 15);
  const int kof = (lane >> 4) * 8;

  for (int kt = 0; kt < K; kt += 32) {
    gload16(ga0, la0); gload16(ga1, la1);
    gload16(gb0, lb0); gload16(gb1, lb1);
    ga0 += 32; ga1 += 32; gb0 += 32; gb1 += 32;
    __syncthreads();
    bf16x8 af[4], bfr[4];
#pragma unroll
    for (int mi = 0; mi < 4; mi++)
      af[mi] = *(const bf16x8*)(As + (arow + mi * 16) * 32 + kof);
#pragma unroll
    for (int ni = 0; ni < 4; ni++)
      bfr[ni] = *(const bf16x8*)(Bs + (brow + ni * 16) * 32 + kof);
#pragma unroll
    for (int mi = 0; mi < 4; mi++)
#pragma unroll
      for (int ni = 0; ni < 4; ni++)
        acc[mi][ni] = __builtin_amdgcn_mfma_f32_16x16x32_bf16(af[mi], bfr[ni], acc[mi][ni], 0, 0, 0);
    __syncthreads();
  }

  // epilogue: C/D mapping col=lane&15, row=(lane>>4)*4+reg
  const int crow = wr + ((lane >> 4) << 2);  // + mi*16 + rr
  const int ccol = wc + (lane & 15);         // + ni*16
  if (EPI == 0) {
    unsigned short* Co = (unsigned short*)Cv + (long)bz * sC;
#pragma unroll
    for (int mi = 0; mi < 4; mi++)
#pragma unroll
      for (int rr = 0; rr < 4; rr++) {
        long row = m0 + crow + mi * 16 + rr;
#pragma unroll
        for (int ni = 0; ni < 4; ni++) {
          long col = n0 + ccol + ni * 16;
          float v = acc[mi][ni][rr];
          if (bias) v += bias[col];
          Co[row * ldc + col] = f2bf(v);
        }
      }
  } else if (EPI == 1) {
    unsigned short* Co = (unsigned short*)Cv + (long)bz * sC;   // bf16 compact scores
    const int* Mp = mask + (long)bz * sMask;
    const float* rtb = rt + (long)bz * NN;
    float* edpart = (float*)As;   // LDS free (K-loop ended with syncthreads)
    if (t < 128) edpart[t] = 0.f;
    __syncthreads();
    float wec[4];
#pragma unroll
    for (int ni = 0; ni < 4; ni++) wec[ni] = We[n0 + ccol + ni * 16];
#pragma unroll
    for (int mi = 0; mi < 4; mi++) {
      float pr[4];
#pragma unroll
      for (int rr = 0; rr < 4; rr++) {
        int row_l = crow + mi * 16 + rr;
        long row = m0 + row_l;
        float rv = rtb[row];
        float pv = 0.f;
#pragma unroll
        for (int ni = 0; ni < 4; ni++) {
          long col = n0 + ccol + ni * 16;
          float sm = (acc[mi][ni][rr] + rv) * scale + (float)Mp[row * ldc + col] * -1e9f;
          Co[row * ldc + col] = f2bf(sm);
          pv += sm * wec[ni];
        }
        pr[rr] = pv;
      }
      // reduce over the 16 col-lanes (shfl_xor masks stay within the 16-lane group)
#pragma unroll
      for (int mask_ = 1; mask_ < 16; mask_ <<= 1)
#pragma unroll
        for (int rr = 0; rr < 4; rr++) pr[rr] += __shfl_xor(pr[rr], mask_);
      if ((lane & 15) == 0) {
#pragma unroll
        for (int rr = 0; rr < 4; rr++)
          atomicAdd(&edpart[crow + mi * 16 + rr], pr[rr]);
      }
    }
    __syncthreads();
    if (t < 128) atomicAdd(&edot[(long)bz * NN + m0 + t], edpart[t]);
  } else {
    float* Co = (float*)Cv + (long)bz * sC;
#pragma unroll
    for (int mi = 0; mi < 4; mi++)
#pragma unroll
      for (int rr = 0; rr < 4; rr++) {
        long row = m0 + crow + mi * 16 + rr;
#pragma unroll
        for (int ni = 0; ni < 4; ni++) {
          long col = n0 + ccol + ni * 16;
          Co[row * ldc + col] = acc[mi][ni][rr] + bias[col];
        }
      }
  }
}

// ---------- edge gate + softmax on compact bf16 scores, in place ----------
__global__ __launch_bounds__(256) void k_edge_softmax(unsigned short* __restrict__ attn,
                                                      const float* __restrict__ edot,
                                                      const float* __restrict__ be) {
  __shared__ float r2[4], r3[4];
  const long row = blockIdx.x;
  unsigned short* srow = attn + row * (long)NN;
  const int t = threadIdx.x;
  const int lane = t & 63;
  const int w = t >> 6;

  float edge = 1.0f / (1.0f + expf(-(edot[row] + be[0])));
  ushort8 v = *(const ushort8*)(srow + t * 8);
  float s[8];
  float mx = -3.4e38f;
#pragma unroll
  for (int j = 0; j < 8; j++) { s[j] = bf2f(v[j]) * edge; mx = fmaxf(mx, s[j]); }
#pragma unroll
  for (int off = 32; off >= 1; off >>= 1) mx = fmaxf(mx, __shfl_down(mx, off));
  if (lane == 0) r2[w] = mx;
  __syncthreads();
  mx = fmaxf(fmaxf(r2[0], r2[1]), fmaxf(r2[2], r2[3]));

  float sum = 0.f;
  float p[8];
#pragma unroll
  for (int j = 0; j < 8; j++) { p[j] = expf(s[j] - mx); sum += p[j]; }
#pragma unroll
  for (int off = 32; off >= 1; off >>= 1) sum += __shfl_down(sum, off);
  if (lane == 0) r3[w] = sum;
  __syncthreads();
  sum = r3[0] + r3[1] + r3[2] + r3[3];
  float inv = 1.0f / sum;

  ushort8 o;
#pragma unroll
  for (int j = 0; j < 8; j++) o[j] = f2bf(p[j] * inv);
  *(ushort8*)(srow + t * 8) = o;
}

// ---------- launch ----------
extern "C" void kernel_launch(void* const* d_in, const int* in_sizes, int n_in,
                              void* d_out, int out_size, void* d_ws, size_t ws_size,
                              hipStream_t stream) {
  (void)in_sizes; (void)n_in; (void)out_size; (void)ws_size;
  const float* query = (const float*)d_in[0];
  const float* key_  = (const float*)d_in[1];
  const float* value = (const float*)d_in[2];
  const int*   mask  = (const int*)d_in[3];
  const float* Wq = (const float*)d_in[4];
  const float* bq = (const float*)d_in[5];
  const float* Wk = (const float*)d_in[6];
  const float* bk = (const float*)d_in[7];
  const float* Wv = (const float*)d_in[8];
  const float* bv = (const float*)d_in[9];
  const float* We = (const float*)d_in[10];
  const float* be = (const float*)d_in[11];
  const float* Wo = (const float*)d_in[12];
  const float* bo = (const float*)d_in[13];
  float* out = (float*)d_out;

  const long WSZ = (long)EE * EE;
  char* ws = (char*)d_ws;
  unsigned short* WkT = (unsigned short*)(ws);
  unsigned short* Wob = WkT + WSZ;
  unsigned short* WqT = WkT + 2 * WSZ;
  unsigned short* WvT = WkT + 3 * WSZ;
  unsigned short* W2T = (unsigned short*)(ws + 33554432L);
  unsigned short* W3T = W2T + WSZ;
  unsigned short* attn = (unsigned short*)(ws);
  unsigned short* qb  = (unsigned short*)(ws + 79691776L);
  unsigned short* kb  = (unsigned short*)(ws + 114294784L);
  unsigned short* vb  = (unsigned short*)(ws + 148897792L);
  unsigned short* Tb  = vb;
  unsigned short* Vt2 = (unsigned short*)(ws + 183500800L);
  unsigned short* Vt2T = qb;
  float* cvec = (float*)(ws + 219938816L);
  float* uvec = cvec + EE;
  float* w2b  = cvec + 2 * EE;
  float* t4   = cvec + 3 * EE;
  float* rt   = cvec + 3 * EE + 64;
  float* edot = rt + (long)BB * NN;

  const float scale = 1.0f / sqrtf((float)EE);
  dim3 blk(256), blk5(512);

  // weights: fused fp32->bf16 transposed (Wk,Wq,Wv in ONE dispatch); Wo plain convert
  k_trf2b3<<<dim3(32, 32, 3), blk, 0, stream>>>(Wk, Wq, Wv, WkT, WqT, WvT);
  k_f32_to_bf16<<<2048, blk, 0, stream>>>(Wo, Wob);
  // bias vectors
  hipMemsetAsync(uvec, 0, (2 * EE + 64) * sizeof(float), stream);
  hipMemsetAsync(edot, 0, (long)BB * NN * sizeof(float), stream);
  k_vecw<<<dim3(8, 32), blk, 0, stream>>>(Wq, Wk, bq, bk, uvec, w2b, t4);
  k_cvec<<<512, blk, 0, stream>>>(Wo, bv, bo, cvec);
  // fused weight GEMMs z=2: z0: W2T = WkT.WqT^T;  z1: W3T = Wob.WvT^T
  k_gemm128<<<dim3(16, 16, 2), blk5, 0, stream>>>(WkT, EE, WSZ, WqT, EE, WSZ,
      W2T, EE, WSZ, EE);
  // data -> bf16 (q,k,v in ONE dispatch)
  k_conv3<<<dim3(8192, 1, 3), blk, 0, stream>>>(query, key_, value, qb, kb, vb);
  // Vt2 = v @ W3   [m97 kernel: 1024 wg = 4 blocks/CU]
  k_gemm97<0><<<dim3(16, 64, 1), blk, 0, stream>>>(vb, EE, 0, W3T, EE, 0,
      Vt2, EE, 0, EE, nullptr, nullptr, 0, nullptr, 0.f, nullptr, nullptr);
  // T = q @ W2 + w2b  -> Tb (vb region dead)
  k_gemm97<0><<<dim3(16, 64, 1), blk, 0, stream>>>(qb, EE, 0, W2T, EE, 0,
      Tb, EE, 0, EE, w2b, nullptr, 0, nullptr, 0.f, nullptr, nullptr);
  // rowterm (reads qb; before Vt2T overwrites qb)
  k_rowterm<<<2048, blk, 0, stream>>>(qb, uvec, t4, rt);
  // Vt2T = transpose(Vt2) per batch -> qb region
  k_transpose<<<dim3(32, 32, BB), blk, 0, stream>>>(Vt2, Vt2T);
  // scores -> compact bf16 attn + edge-dot accumulation (fp32)
  k_gemm97<1><<<dim3(16, 16, BB), blk, 0, stream>>>(Tb, EE, (long)NN * EE, kb, EE, (long)NN * EE,
      attn, NN, (long)NN * NN, EE, nullptr, mask, (long)NN * NN, rt, scale, We, edot);
  // edge gate + softmax in place (compact bf16)
  k_edge_softmax<<<BB * NN, blk, 0, stream>>>(attn, edot, be);
  // out = attn @ Vt2 + cvec
  k_gemm97<2><<<dim3(16, 16, BB), blk, 0, stream>>>(attn, NN, (long)NN * NN,
      Vt2T, NN, (long)EE * NN, out, EE, (long)NN * EE, NN,
      cvec, nullptr, 0, nullptr, 0.f, nullptr, nullptr);
}

// Round 14
// 470.471 us; speedup vs baseline: 1.3849x; 1.3849x over previous
//
#include <hip/hip_runtime.h>
#include <math.h>

#define BB 4
#define NN 2048
#define EE 2048

typedef __attribute__((ext_vector_type(8))) unsigned short ushort8;
typedef __attribute__((ext_vector_type(8))) __bf16 bf16x8;
typedef __attribute__((ext_vector_type(4))) float f32x4;

// ---------- helpers ----------
__device__ __forceinline__ unsigned short f2bf(float f) {
  unsigned int u = __float_as_uint(f);
  u = u + 0x7fffu + ((u >> 16) & 1u);   // RNE; inputs are finite
  return (unsigned short)(u >> 16);
}
__device__ __forceinline__ float bf2f(unsigned short h) {
  return __uint_as_float((unsigned)h << 16);
}

__device__ __forceinline__ void gload16(const void* g, void* l) {
  __builtin_amdgcn_global_load_lds(
      (__attribute__((address_space(1))) void*)g,
      (__attribute__((address_space(3))) void*)l, 16, 0, 0);
}

#define BARRIER() __builtin_amdgcn_s_barrier()
#define WAIT_VM(N) asm volatile("s_waitcnt vmcnt(" #N ")")

// ---------- fp32 -> bf16 conversion (vectorized) ----------
__global__ __launch_bounds__(256) void k_f32_to_bf16(const float* __restrict__ in,
                                                     unsigned short* __restrict__ out) {
  size_t i = (size_t)blockIdx.x * 256 + threadIdx.x;   // 8 elems each
  const float4* ip = (const float4*)in;
  float4 a = ip[i * 2];
  float4 b = ip[i * 2 + 1];
  ushort8 o;
  o[0] = f2bf(a.x); o[1] = f2bf(a.y); o[2] = f2bf(a.z); o[3] = f2bf(a.w);
  o[4] = f2bf(b.x); o[5] = f2bf(b.y); o[6] = f2bf(b.z); o[7] = f2bf(b.w);
  *((ushort8*)out + i) = o;
}

// ---------- fused q/k/v conversion, one dispatch (z selects tensor) ----------
__global__ __launch_bounds__(256) void k_conv3(const float* __restrict__ s0,
                                               const float* __restrict__ s1,
                                               const float* __restrict__ s2,
                                               unsigned short* __restrict__ d0,
                                               unsigned short* __restrict__ d1,
                                               unsigned short* __restrict__ d2) {
  const float* in; unsigned short* out;
  if (blockIdx.z == 0) { in = s0; out = d0; }
  else if (blockIdx.z == 1) { in = s1; out = d1; }
  else { in = s2; out = d2; }
  size_t i = (size_t)blockIdx.x * 256 + threadIdx.x;
  const float4* ip = (const float4*)in;
  float4 a = ip[i * 2];
  float4 b = ip[i * 2 + 1];
  ushort8 o;
  o[0] = f2bf(a.x); o[1] = f2bf(a.y); o[2] = f2bf(a.z); o[3] = f2bf(a.w);
  o[4] = f2bf(b.x); o[5] = f2bf(b.y); o[6] = f2bf(b.z); o[7] = f2bf(b.w);
  *((ushort8*)out + i) = o;
}

// ---------- fused fp32 read -> bf16 transposed write, 3 weights in one dispatch ----------
__global__ __launch_bounds__(256) void k_trf2b3(const float* __restrict__ s0,
                                                const float* __restrict__ s1,
                                                const float* __restrict__ s2,
                                                unsigned short* __restrict__ d0,
                                                unsigned short* __restrict__ d1,
                                                unsigned short* __restrict__ d2) {
  __shared__ __attribute__((aligned(16))) unsigned short tile[64][72];
  const float* in; unsigned short* out;
  if (blockIdx.z == 0) { in = s0; out = d0; }
  else if (blockIdx.z == 1) { in = s1; out = d1; }
  else { in = s2; out = d2; }
  const long eb = (long)blockIdx.x * 64;
  const long nb = (long)blockIdx.y * 64;
  const int t = threadIdx.x;
  const int r = t >> 3;
  const int c = (t & 7) * 8;

  const float* p0 = in + (nb + r) * (long)EE + eb + c;
  const float* p1 = in + (nb + 32 + r) * (long)EE + eb + c;
  float4 a0 = *(const float4*)p0, a1 = *(const float4*)(p0 + 4);
  float4 b0 = *(const float4*)p1, b1 = *(const float4*)(p1 + 4);
  unsigned short* t0 = &tile[r][c];
  unsigned short* t1 = &tile[r + 32][c];
  t0[0] = f2bf(a0.x); t0[1] = f2bf(a0.y); t0[2] = f2bf(a0.z); t0[3] = f2bf(a0.w);
  t0[4] = f2bf(a1.x); t0[5] = f2bf(a1.y); t0[6] = f2bf(a1.z); t0[7] = f2bf(a1.w);
  t1[0] = f2bf(b0.x); t1[1] = f2bf(b0.y); t1[2] = f2bf(b0.z); t1[3] = f2bf(b0.w);
  t1[4] = f2bf(b1.x); t1[5] = f2bf(b1.y); t1[6] = f2bf(b1.z); t1[7] = f2bf(b1.w);
  __syncthreads();
  ushort8 o0, o1;
#pragma unroll
  for (int j = 0; j < 8; j++) { o0[j] = tile[c + j][r]; o1[j] = tile[c + j][r + 32]; }
  *(ushort8*)(out + (eb + r) * (long)NN + nb + c) = o0;
  *(ushort8*)(out + (eb + r + 32) * (long)NN + nb + c) = o1;
}

// ---------- bf16 transpose [R,C] -> [C,R] per batch z ----------
__global__ __launch_bounds__(256) void k_transpose(const unsigned short* __restrict__ in,
                                                   unsigned short* __restrict__ out) {
  __shared__ __attribute__((aligned(16))) unsigned short tile[64][72];
  const long z = blockIdx.z;
  const long eb = (long)blockIdx.x * 64;
  const long nb = (long)blockIdx.y * 64;
  const unsigned short* ip = in + z * (long)NN * EE;
  unsigned short* op = out + z * (long)NN * EE;
  const int t = threadIdx.x;
  const int r = t >> 3;
  const int c = (t & 7) * 8;

  ushort8 u0 = *(const ushort8*)(ip + (nb + r) * EE + eb + c);
  ushort8 u1 = *(const ushort8*)(ip + (nb + 32 + r) * EE + eb + c);
  *(ushort8*)&tile[r][c] = u0;
  *(ushort8*)&tile[r + 32][c] = u1;
  __syncthreads();
  ushort8 o0, o1;
#pragma unroll
  for (int j = 0; j < 8; j++) { o0[j] = tile[c + j][r]; o1[j] = tile[c + j][r + 32]; }
  *(ushort8*)(op + (eb + r) * NN + nb + c) = o0;
  *(ushort8*)(op + (eb + r + 32) * NN + nb + c) = o1;
}

// ---------- bias precompute (general-bias; zeros in this input set) ----------
__global__ __launch_bounds__(256) void k_vecw(const float* __restrict__ Wq,
                                              const float* __restrict__ Wk,
                                              const float* __restrict__ bq,
                                              const float* __restrict__ bk,
                                              float* __restrict__ u,
                                              float* __restrict__ w2b,
                                              float* __restrict__ t4) {
  const int e = blockIdx.x * 256 + threadIdx.x;
  const int tt0 = blockIdx.y * 64;
  float su = 0.f, sw = 0.f;
#pragma unroll 4
  for (int i = 0; i < 64; i++) {
    int tt = tt0 + i;
    su += Wq[(long)tt * EE + e] * bk[tt];
    sw += Wk[(long)tt * EE + e] * bq[tt];
  }
  atomicAdd(&u[e], su);
  atomicAdd(&w2b[e], sw);
  if (blockIdx.x == 0 && threadIdx.x < 64) {
    int lane = threadIdx.x;
    float p = bq[tt0 + lane] * bk[tt0 + lane];
    for (int off = 32; off >= 1; off >>= 1) p += __shfl_down(p, off);
    if (lane == 0) atomicAdd(t4, p);
  }
}

__global__ __launch_bounds__(256) void k_cvec(const float* __restrict__ Wo,
                                              const float* __restrict__ bv,
                                              const float* __restrict__ bo,
                                              float* __restrict__ cv) {
  int row = blockIdx.x * 4 + (threadIdx.x >> 6);
  int lane = threadIdx.x & 63;
  float s = 0.f;
  for (int j = lane; j < EE; j += 64) s += Wo[(long)row * EE + j] * bv[j];
  for (int off = 32; off >= 1; off >>= 1) s += __shfl_down(s, off);
  if (lane == 0) cv[row] = s + bo[row];
}

__global__ __launch_bounds__(256) void k_rowterm(const unsigned short* __restrict__ qb,
                                                 const float* __restrict__ u,
                                                 const float* __restrict__ t4,
                                                 float* __restrict__ rt) {
  long row = (long)blockIdx.x * 4 + (threadIdx.x >> 6);
  int lane = threadIdx.x & 63;
  const unsigned short* qr = qb + row * EE;
  float s = 0.f;
#pragma unroll
  for (int it = 0; it < 4; ++it) {
    int e0 = it * 512 + lane * 8;
    ushort8 qv = *(const ushort8*)(qr + e0);
#pragma unroll
    for (int j = 0; j < 8; j++) s += bf2f(qv[j]) * u[e0 + j];
  }
  for (int off = 32; off >= 1; off >>= 1) s += __shfl_down(s, off);
  if (lane == 0) rt[row] = s + *t4;
}

// ---------- 128x128-tile GEMM for the z=2 weight precompute (512 wg) ----------
__global__ __launch_bounds__(512, 4) void k_gemm128(
    const unsigned short* __restrict__ A, long lda, long sA,
    const unsigned short* __restrict__ Bm, long ldb, long sB,
    unsigned short* __restrict__ Co, long ldc, long sC, int K) {
  __shared__ __attribute__((aligned(16))) unsigned short As[2 * 8192];
  __shared__ __attribute__((aligned(16))) unsigned short Bs[2 * 8192];
  const int gx = gridDim.x, gy = gridDim.y;
  int lin = (int)blockIdx.x + gx * ((int)blockIdx.y + gy * (int)blockIdx.z);
  int nwg = gx * gy * (int)gridDim.z;
  int chunk = nwg >> 3;
  int sw = (lin & 7) * chunk + (lin >> 3);
  int bz = sw / (gx * gy); int rem = sw - bz * (gx * gy);
  int by = rem / gx; int bx = rem - by * gx;

  const long m0 = (long)by * 128;
  const long n0 = (long)bx * 128;
  const unsigned short* Ab = A + (long)bz * sA;
  const unsigned short* Bb = Bm + (long)bz * sB;
  const int t = threadIdx.x;
  const int lane = t & 63;
  const int w = t >> 6;
  const int wm = w >> 2, wn = w & 3;

  const int srow = t >> 3;
  const int scol = (((t & 7) * 16) ^ (((t >> 5) & 1) << 5)) >> 1;
  const unsigned short* Ga = Ab + (m0 + srow) * lda + scol;
  const unsigned short* Gb = Bb + (n0 + srow) * ldb + scol;
  const int ldst = t * 8;

#define STAGE(buf, tile) do { \
    const unsigned short* ga_ = Ga + (long)(tile) * 64; \
    const unsigned short* gb_ = Gb + (long)(tile) * 64; \
    unsigned short* la_ = As + (buf) * 8192 + ldst; \
    unsigned short* lb_ = Bs + (buf) * 8192 + ldst; \
    gload16(ga_, la_); gload16(ga_ + 64 * lda, la_ + 4096); \
    gload16(gb_, lb_); gload16(gb_ + 64 * ldb, lb_ + 4096); \
  } while (0)

  const int r = lane & 15;
  const int q = lane >> 4;
  const int rb2 = ((r * 128 + q * 16) ^ ((r & 4) << 3)) >> 1;
  const int aBase = wm * 4096 + rb2;
  const int bBase = wn * 2048 + rb2;

  f32x4 acc[4][2] = {};
  bf16x8 a[4][2], b[2][2];
  const int J = K >> 6;
  STAGE(0, 0);
  WAIT_VM(0);
  BARRIER();
  for (int j = 0; j < J; ++j) {
    const int c = j & 1;
    const unsigned short* Ac = As + c * 8192;
    const unsigned short* Bc = Bs + c * 8192;
#pragma unroll
    for (int mi = 0; mi < 4; mi++)
#pragma unroll
      for (int kk = 0; kk < 2; kk++)
        a[mi][kk] = *(const bf16x8*)(Ac + aBase + mi * 1024 + kk * 32);
#pragma unroll
    for (int ni = 0; ni < 2; ni++)
#pragma unroll
      for (int kk = 0; kk < 2; kk++)
        b[ni][kk] = *(const bf16x8*)(Bc + bBase + ni * 1024 + kk * 32);
    if (j + 1 < J) STAGE(c ^ 1, j + 1);
    __builtin_amdgcn_s_setprio(1);
#pragma unroll
    for (int mi = 0; mi < 4; mi++)
#pragma unroll
      for (int ni = 0; ni < 2; ni++)
#pragma unroll
        for (int kk = 0; kk < 2; kk++)
          acc[mi][ni] = __builtin_amdgcn_mfma_f32_16x16x32_bf16(
              a[mi][kk], b[ni][kk], acc[mi][ni], 0, 0, 0);
    __builtin_amdgcn_s_setprio(0);
    WAIT_VM(0);
    BARRIER();
  }
#undef STAGE
  const int cr0 = wm * 64 + (q << 2);
  const int cc0 = wn * 32 + r;
#pragma unroll
  for (int mi = 0; mi < 4; mi++)
#pragma unroll
    for (int rr = 0; rr < 4; rr++) {
      long row = m0 + cr0 + mi * 16 + rr;
#pragma unroll
      for (int ni = 0; ni < 2; ni++)
        Co[(long)bz * sC + row * ldc + n0 + cc0 + ni * 16] = f2bf(acc[mi][ni][rr]);
    }
}

// ---------- 256x256 8-wave 8-phase GEMM, 16x16x32 MFMA (measured-best) ----------
// EPI 0: bf16 out (+bias[col])
// EPI 1: scores: sm=(acc+rt)*scale+mask*(-1e9); store bf16 compact; edge-dot from
//        fp32 sm via r-lane shfl reduce + LDS(reused As) + global atomicAdd(edot)
// EPI 2: f32 out + bias[col]
template <int EPI>
__global__ __launch_bounds__(512, 2) void k_gemm256(
    const unsigned short* __restrict__ A, long lda, long sA,
    const unsigned short* __restrict__ Bm, long ldb, long sB,
    void* __restrict__ Cv, long ldc, long sC, int K,
    const float* __restrict__ bias,
    const int* __restrict__ mask, long sMask,
    const float* __restrict__ rt, float scale,
    const float* __restrict__ We, float* __restrict__ edot) {
  __shared__ __attribute__((aligned(16))) unsigned short As[2 * 16384];
  __shared__ __attribute__((aligned(16))) unsigned short Bs[2 * 16384];

  const int gx = gridDim.x, gy = gridDim.y;
  int lin = (int)blockIdx.x + gx * ((int)blockIdx.y + gy * (int)blockIdx.z);
  int nwg = gx * gy * (int)gridDim.z;
  int chunk = nwg >> 3;
  int sw = (lin & 7) * chunk + (lin >> 3);
  int bz = sw / (gx * gy); int rem = sw - bz * (gx * gy);
  int by = rem / gx; int bx = rem - by * gx;

  const long m0 = (long)by * 256;
  const long n0 = (long)bx * 256;
  const unsigned short* Ab = A + (long)bz * sA;
  const unsigned short* Bb = Bm + (long)bz * sB;

  const int t = threadIdx.x;
  const int lane = t & 63;
  const int w = t >> 6;
  const int wm = w >> 2;
  const int wn = w & 3;

  const int p0 = t * 16;
  const int q0 = p0 ^ (((p0 >> 9) & 1) << 5);
  const int srow = ((q0 >> 10) >> 1) * 16 + ((q0 >> 6) & 15);
  const int scol = ((q0 >> 10) & 1) * 32 + ((q0 & 63) >> 1);
  const unsigned short* Ga = Ab + (m0 + srow) * lda + scol;
  const unsigned short* Gb = Bb + (n0 + srow) * ldb + scol;
  const int ldst = t * 8;

#define STAGE_A(buf, h, tile) do { \
    const unsigned short* g_ = Ga + (long)(tile) * 64 + (long)(h) * 128 * lda; \
    unsigned short* l_ = As + (buf) * 16384 + (h) * 8192 + ldst; \
    gload16(g_, l_); gload16(g_ + 64 * lda, l_ + 4096); \
  } while (0)
#define STAGE_B(buf, h, tile) do { \
    const unsigned short* g_ = Gb + (long)(tile) * 64 + (long)(h) * 128 * ldb; \
    unsigned short* l_ = Bs + (buf) * 16384 + (h) * 8192 + ldst; \
    gload16(g_, l_); gload16(g_ + 64 * ldb, l_ + 4096); \
  } while (0)

  const int r = lane & 15;
  const int q = lane >> 4;
  const int c2h = ((q * 16) ^ (((lane >> 3) & 1) << 5)) >> 1;
  const int aBase = wm * 8192 + r * 32 + c2h;
  const int bBase = (wn >> 1) * 8192 + (wn & 1) * 4096 + r * 32 + c2h;

#define RD_A(bp, mbase) do { \
    _Pragma("unroll") for (int mi = 0; mi < 4; mi++) \
    _Pragma("unroll") for (int kk = 0; kk < 2; kk++) \
      a[mi][kk] = *(const bf16x8*)((bp) + aBase + ((mbase) + mi) * 1024 + kk * 512); \
  } while (0)
#define RD_B(bp, nbase) do { \
    _Pragma("unroll") for (int ni = 0; ni < 2; ni++) \
    _Pragma("unroll") for (int kk = 0; kk < 2; kk++) \
      b[(nbase) + ni][kk] = *(const bf16x8*)((bp) + bBase + ((nbase) + ni) * 1024 + kk * 512); \
  } while (0)
#define MFMA_Q(mbase, nbase) do { \
    BARRIER(); \
    __builtin_amdgcn_s_setprio(1); \
    _Pragma("unroll") for (int mi = 0; mi < 4; mi++) \
    _Pragma("unroll") for (int ni = 0; ni < 2; ni++) \
    _Pragma("unroll") for (int kk = 0; kk < 2; kk++) \
      acc[(mbase) + mi][(nbase) + ni] = __builtin_amdgcn_mfma_f32_16x16x32_bf16( \
          a[mi][kk], b[(nbase) + ni][kk], acc[(mbase) + mi][(nbase) + ni], 0, 0, 0); \
    __builtin_amdgcn_s_setprio(0); \
    BARRIER(); \
  } while (0)

  f32x4 acc[8][4] = {};
  bf16x8 a[4][2], b[4][2];
  const unsigned short* A0 = As;
  const unsigned short* B0 = Bs;
  const unsigned short* A1 = As + 16384;
  const unsigned short* B1 = Bs + 16384;
  const int J = K >> 7;

  STAGE_B(0, 0, 0); STAGE_B(0, 1, 0);
  STAGE_A(0, 0, 0); STAGE_A(0, 1, 0);
  STAGE_B(1, 0, 1); STAGE_B(1, 1, 1);
  WAIT_VM(4);
  BARRIER();

  for (int j = 0; j < J; ++j) {
    const int t0 = 2 * j, t1 = 2 * j + 1;
    const bool pf = (j + 1 < J);

    RD_A(A0, 0); RD_B(B0, 0);
    STAGE_A(1, 0, t1);
    MFMA_Q(0, 0);

    RD_B(B0, 2);
    STAGE_A(1, 1, t1);
    MFMA_Q(0, 2);

    RD_A(A0, 4);
    if (pf) STAGE_B(0, 0, t0 + 2);
    MFMA_Q(4, 0);

    if (pf) { STAGE_B(0, 1, t0 + 2); WAIT_VM(4); } else { WAIT_VM(0); }
    MFMA_Q(4, 2);

    RD_A(A1, 0); RD_B(B1, 0);
    if (pf) STAGE_A(0, 0, t0 + 2);
    MFMA_Q(0, 0);

    RD_B(B1, 2);
    if (pf) STAGE_A(0, 1, t0 + 2);
    MFMA_Q(0, 2);

    RD_A(A1, 4);
    if (pf) STAGE_B(1, 0, t1 + 2);
    MFMA_Q(4, 0);

    if (pf) { STAGE_B(1, 1, t1 + 2); WAIT_VM(4); }
    MFMA_Q(4, 2);
  }
#undef STAGE_A
#undef STAGE_B
#undef RD_A
#undef RD_B
#undef MFMA_Q

  const int cr0 = wm * 128 + (q << 2);
  const int cc0 = wn * 64 + r;
  if (EPI == 0) {
    unsigned short* Co = (unsigned short*)Cv + (long)bz * sC;
#pragma unroll
    for (int mi = 0; mi < 8; mi++)
#pragma unroll
      for (int rr = 0; rr < 4; rr++) {
        long row = m0 + cr0 + mi * 16 + rr;
#pragma unroll
        for (int ni = 0; ni < 4; ni++) {
          long col = n0 + cc0 + ni * 16;
          float v = acc[mi][ni][rr];
          if (bias) v += bias[col];
          Co[row * ldc + col] = f2bf(v);
        }
      }
  } else if (EPI == 1) {
    unsigned short* Co = (unsigned short*)Cv + (long)bz * sC;   // bf16 compact scores
    const int* Mp = mask + (long)bz * sMask;
    const float* rtb = rt + (long)bz * NN;
    float* edpart = (float*)As;   // LDS dead after K-loop; final BARRIER synced all waves
    if (t < 256) edpart[t] = 0.f;
    __syncthreads();
    float wec[4];
#pragma unroll
    for (int ni = 0; ni < 4; ni++) wec[ni] = We[n0 + cc0 + ni * 16];
#pragma unroll
    for (int mi = 0; mi < 8; mi++) {
      float pr[4];
#pragma unroll
      for (int rr = 0; rr < 4; rr++) {
        long row = m0 + cr0 + mi * 16 + rr;
        float rv = rtb[row];
        float pv = 0.f;
#pragma unroll
        for (int ni = 0; ni < 4; ni++) {
          long col = n0 + cc0 + ni * 16;
          float sm = (acc[mi][ni][rr] + rv) * scale + (float)Mp[row * ldc + col] * -1e9f;
          Co[row * ldc + col] = f2bf(sm);
          pv += sm * wec[ni];
        }
        pr[rr] = pv;
      }
#pragma unroll
      for (int mask_ = 1; mask_ < 16; mask_ <<= 1)
#pragma unroll
        for (int rr = 0; rr < 4; rr++) pr[rr] += __shfl_xor(pr[rr], mask_);
      if (r == 0) {
#pragma unroll
        for (int rr = 0; rr < 4; rr++)
          atomicAdd(&edpart[cr0 + mi * 16 + rr], pr[rr]);
      }
    }
    __syncthreads();
    if (t < 256) atomicAdd(&edot[(long)bz * NN + m0 + t], edpart[t]);
  } else {
    float* Co = (float*)Cv + (long)bz * sC;
#pragma unroll
    for (int mi = 0; mi < 8; mi++)
#pragma unroll
      for (int rr = 0; rr < 4; rr++) {
        long row = m0 + cr0 + mi * 16 + rr;
#pragma unroll
        for (int ni = 0; ni < 4; ni++) {
          long col = n0 + cc0 + ni * 16;
          Co[row * ldc + col] = acc[mi][ni][rr] + bias[col];
        }
      }
  }
}

// ---------- edge gate + softmax on compact bf16 scores, in place ----------
__global__ __launch_bounds__(256) void k_edge_softmax(unsigned short* __restrict__ attn,
                                                      const float* __restrict__ edot,
                                                      const float* __restrict__ be) {
  __shared__ float r2[4], r3[4];
  const long row = blockIdx.x;
  unsigned short* srow = attn + row * (long)NN;
  const int t = threadIdx.x;
  const int lane = t & 63;
  const int w = t >> 6;

  float edge = 1.0f / (1.0f + expf(-(edot[row] + be[0])));
  ushort8 v = *(const ushort8*)(srow + t * 8);
  float s[8];
  float mx = -3.4e38f;
#pragma unroll
  for (int j = 0; j < 8; j++) { s[j] = bf2f(v[j]) * edge; mx = fmaxf(mx, s[j]); }
#pragma unroll
  for (int off = 32; off >= 1; off >>= 1) mx = fmaxf(mx, __shfl_down(mx, off));
  if (lane == 0) r2[w] = mx;
  __syncthreads();
  mx = fmaxf(fmaxf(r2[0], r2[1]), fmaxf(r2[2], r2[3]));

  float sum = 0.f;
  float p[8];
#pragma unroll
  for (int j = 0; j < 8; j++) { p[j] = expf(s[j] - mx); sum += p[j]; }
#pragma unroll
  for (int off = 32; off >= 1; off >>= 1) sum += __shfl_down(sum, off);
  if (lane == 0) r3[w] = sum;
  __syncthreads();
  sum = r3[0] + r3[1] + r3[2] + r3[3];
  float inv = 1.0f / sum;

  ushort8 o;
#pragma unroll
  for (int j = 0; j < 8; j++) o[j] = f2bf(p[j] * inv);
  *(ushort8*)(srow + t * 8) = o;
}

// ---------- launch ----------
extern "C" void kernel_launch(void* const* d_in, const int* in_sizes, int n_in,
                              void* d_out, int out_size, void* d_ws, size_t ws_size,
                              hipStream_t stream) {
  (void)in_sizes; (void)n_in; (void)out_size; (void)ws_size;
  const float* query = (const float*)d_in[0];
  const float* key_  = (const float*)d_in[1];
  const float* value = (const float*)d_in[2];
  const int*   mask  = (const int*)d_in[3];
  const float* Wq = (const float*)d_in[4];
  const float* bq = (const float*)d_in[5];
  const float* Wk = (const float*)d_in[6];
  const float* bk = (const float*)d_in[7];
  const float* Wv = (const float*)d_in[8];
  const float* bv = (const float*)d_in[9];
  const float* We = (const float*)d_in[10];
  const float* be = (const float*)d_in[11];
  const float* Wo = (const float*)d_in[12];
  const float* bo = (const float*)d_in[13];
  float* out = (float*)d_out;

  const long WSZ = (long)EE * EE;
  char* ws = (char*)d_ws;
  unsigned short* WkT = (unsigned short*)(ws);
  unsigned short* Wob = WkT + WSZ;
  unsigned short* WqT = WkT + 2 * WSZ;
  unsigned short* WvT = WkT + 3 * WSZ;
  unsigned short* W2T = (unsigned short*)(ws + 33554432L);
  unsigned short* W3T = W2T + WSZ;
  unsigned short* attn = (unsigned short*)(ws);
  unsigned short* qb  = (unsigned short*)(ws + 79691776L);
  unsigned short* kb  = (unsigned short*)(ws + 114294784L);
  unsigned short* vb  = (unsigned short*)(ws + 148897792L);
  unsigned short* Tb  = vb;
  unsigned short* Vt2 = (unsigned short*)(ws + 183500800L);
  unsigned short* Vt2T = qb;
  float* cvec = (float*)(ws + 219938816L);
  float* uvec = cvec + EE;
  float* w2b  = cvec + 2 * EE;
  float* t4   = cvec + 3 * EE;
  float* rt   = cvec + 3 * EE + 64;
  float* edot = rt + (long)BB * NN;

  const float scale = 1.0f / sqrtf((float)EE);
  dim3 blk(256), blk5(512);

  // weights: fused fp32->bf16 transposed (Wk,Wq,Wv in ONE dispatch); Wo plain convert
  k_trf2b3<<<dim3(32, 32, 3), blk, 0, stream>>>(Wk, Wq, Wv, WkT, WqT, WvT);
  k_f32_to_bf16<<<2048, blk, 0, stream>>>(Wo, Wob);
  // bias vectors
  hipMemsetAsync(uvec, 0, (2 * EE + 64) * sizeof(float), stream);
  hipMemsetAsync(edot, 0, (long)BB * NN * sizeof(float), stream);
  k_vecw<<<dim3(8, 32), blk, 0, stream>>>(Wq, Wk, bq, bk, uvec, w2b, t4);
  k_cvec<<<512, blk, 0, stream>>>(Wo, bv, bo, cvec);
  // fused weight GEMMs z=2: z0: W2T = WkT.WqT^T;  z1: W3T = Wob.WvT^T
  k_gemm128<<<dim3(16, 16, 2), blk5, 0, stream>>>(WkT, EE, WSZ, WqT, EE, WSZ,
      W2T, EE, WSZ, EE);
  // data -> bf16 (q,k,v in ONE dispatch)
  k_conv3<<<dim3(8192, 1, 3), blk, 0, stream>>>(query, key_, value, qb, kb, vb);
  // Vt2 = v @ W3
  k_gemm256<0><<<dim3(8, 32, 1), blk5, 0, stream>>>(vb, EE, 0, W3T, EE, 0,
      Vt2, EE, 0, EE, nullptr, nullptr, 0, nullptr, 0.f, nullptr, nullptr);
  // T = q @ W2 + w2b  -> Tb (vb region dead)
  k_gemm256<0><<<dim3(8, 32, 1), blk5, 0, stream>>>(qb, EE, 0, W2T, EE, 0,
      Tb, EE, 0, EE, w2b, nullptr, 0, nullptr, 0.f, nullptr, nullptr);
  // rowterm (reads qb; before Vt2T overwrites qb)
  k_rowterm<<<2048, blk, 0, stream>>>(qb, uvec, t4, rt);
  // Vt2T = transpose(Vt2) per batch -> qb region
  k_transpose<<<dim3(32, 32, BB), blk, 0, stream>>>(Vt2, Vt2T);
  // scores -> compact bf16 attn + edge-dot accumulation (fp32)
  k_gemm256<1><<<dim3(8, 8, BB), blk5, 0, stream>>>(Tb, EE, (long)NN * EE, kb, EE, (long)NN * EE,
      attn, NN, (long)NN * NN, EE, nullptr, mask, (long)NN * NN, rt, scale, We, edot);
  // edge gate + softmax in place (compact bf16)
  k_edge_softmax<<<BB * NN, blk, 0, stream>>>(attn, edot, be);
  // out = attn @ Vt2 + cvec
  k_gemm256<2><<<dim3(8, 8, BB), blk5, 0, stream>>>(attn, NN, (long)NN * NN,
      Vt2T, NN, (long)EE * NN, out, EE, (long)NN * EE, NN,
      cvec, nullptr, 0, nullptr, 0.f, nullptr, nullptr);
}

// Round 15
// 428.467 us; speedup vs baseline: 1.5206x; 1.0980x over previous
//
#include <hip/hip_runtime.h>
#include <math.h>

#define BB 4
#define NN 2048
#define EE 2048

typedef __attribute__((ext_vector_type(8))) unsigned short ushort8;
typedef __attribute__((ext_vector_type(8))) __bf16 bf16x8;
typedef __attribute__((ext_vector_type(4))) float f32x4;

// ---------- helpers ----------
__device__ __forceinline__ unsigned short f2bf(float f) {
  unsigned int u = __float_as_uint(f);
  u = u + 0x7fffu + ((u >> 16) & 1u);   // RNE; inputs are finite
  return (unsigned short)(u >> 16);
}
__device__ __forceinline__ float bf2f(unsigned short h) {
  return __uint_as_float((unsigned)h << 16);
}

__device__ __forceinline__ void gload16(const void* g, void* l) {
  __builtin_amdgcn_global_load_lds(
      (__attribute__((address_space(1))) void*)g,
      (__attribute__((address_space(3))) void*)l, 16, 0, 0);
}

#define BARRIER() __builtin_amdgcn_s_barrier()
#define WAIT_VM(N) asm volatile("s_waitcnt vmcnt(" #N ")")

// ---------- fp32 -> bf16 conversion (vectorized) ----------
__global__ __launch_bounds__(256) void k_f32_to_bf16(const float* __restrict__ in,
                                                     unsigned short* __restrict__ out) {
  size_t i = (size_t)blockIdx.x * 256 + threadIdx.x;   // 8 elems each
  const float4* ip = (const float4*)in;
  float4 a = ip[i * 2];
  float4 b = ip[i * 2 + 1];
  ushort8 o;
  o[0] = f2bf(a.x); o[1] = f2bf(a.y); o[2] = f2bf(a.z); o[3] = f2bf(a.w);
  o[4] = f2bf(b.x); o[5] = f2bf(b.y); o[6] = f2bf(b.z); o[7] = f2bf(b.w);
  *((ushort8*)out + i) = o;
}

// ---------- fused q/k/v conversion, one dispatch (z selects tensor) ----------
__global__ __launch_bounds__(256) void k_conv3(const float* __restrict__ s0,
                                               const float* __restrict__ s1,
                                               const float* __restrict__ s2,
                                               unsigned short* __restrict__ d0,
                                               unsigned short* __restrict__ d1,
                                               unsigned short* __restrict__ d2) {
  const float* in; unsigned short* out;
  if (blockIdx.z == 0) { in = s0; out = d0; }
  else if (blockIdx.z == 1) { in = s1; out = d1; }
  else { in = s2; out = d2; }
  size_t i = (size_t)blockIdx.x * 256 + threadIdx.x;
  const float4* ip = (const float4*)in;
  float4 a = ip[i * 2];
  float4 b = ip[i * 2 + 1];
  ushort8 o;
  o[0] = f2bf(a.x); o[1] = f2bf(a.y); o[2] = f2bf(a.z); o[3] = f2bf(a.w);
  o[4] = f2bf(b.x); o[5] = f2bf(b.y); o[6] = f2bf(b.z); o[7] = f2bf(b.w);
  *((ushort8*)out + i) = o;
}

// ---------- fused fp32 read -> bf16 transposed write, 3 weights in one dispatch ----------
__global__ __launch_bounds__(256) void k_trf2b3(const float* __restrict__ s0,
                                                const float* __restrict__ s1,
                                                const float* __restrict__ s2,
                                                unsigned short* __restrict__ d0,
                                                unsigned short* __restrict__ d1,
                                                unsigned short* __restrict__ d2) {
  __shared__ __attribute__((aligned(16))) unsigned short tile[64][72];
  const float* in; unsigned short* out;
  if (blockIdx.z == 0) { in = s0; out = d0; }
  else if (blockIdx.z == 1) { in = s1; out = d1; }
  else { in = s2; out = d2; }
  const long eb = (long)blockIdx.x * 64;
  const long nb = (long)blockIdx.y * 64;
  const int t = threadIdx.x;
  const int r = t >> 3;
  const int c = (t & 7) * 8;

  const float* p0 = in + (nb + r) * (long)EE + eb + c;
  const float* p1 = in + (nb + 32 + r) * (long)EE + eb + c;
  float4 a0 = *(const float4*)p0, a1 = *(const float4*)(p0 + 4);
  float4 b0 = *(const float4*)p1, b1 = *(const float4*)(p1 + 4);
  unsigned short* t0 = &tile[r][c];
  unsigned short* t1 = &tile[r + 32][c];
  t0[0] = f2bf(a0.x); t0[1] = f2bf(a0.y); t0[2] = f2bf(a0.z); t0[3] = f2bf(a0.w);
  t0[4] = f2bf(a1.x); t0[5] = f2bf(a1.y); t0[6] = f2bf(a1.z); t0[7] = f2bf(a1.w);
  t1[0] = f2bf(b0.x); t1[1] = f2bf(b0.y); t1[2] = f2bf(b0.z); t1[3] = f2bf(b0.w);
  t1[4] = f2bf(b1.x); t1[5] = f2bf(b1.y); t1[6] = f2bf(b1.z); t1[7] = f2bf(b1.w);
  __syncthreads();
  ushort8 o0, o1;
#pragma unroll
  for (int j = 0; j < 8; j++) { o0[j] = tile[c + j][r]; o1[j] = tile[c + j][r + 32]; }
  *(ushort8*)(out + (eb + r) * (long)NN + nb + c) = o0;
  *(ushort8*)(out + (eb + r + 32) * (long)NN + nb + c) = o1;
}

// ---------- bias precompute (general-bias; zeros in this input set) ----------
__global__ __launch_bounds__(256) void k_vecw(const float* __restrict__ Wq,
                                              const float* __restrict__ Wk,
                                              const float* __restrict__ bq,
                                              const float* __restrict__ bk,
                                              float* __restrict__ u,
                                              float* __restrict__ w2b,
                                              float* __restrict__ t4) {
  const int e = blockIdx.x * 256 + threadIdx.x;
  const int tt0 = blockIdx.y * 64;
  float su = 0.f, sw = 0.f;
#pragma unroll 4
  for (int i = 0; i < 64; i++) {
    int tt = tt0 + i;
    su += Wq[(long)tt * EE + e] * bk[tt];
    sw += Wk[(long)tt * EE + e] * bq[tt];
  }
  atomicAdd(&u[e], su);
  atomicAdd(&w2b[e], sw);
  if (blockIdx.x == 0 && threadIdx.x < 64) {
    int lane = threadIdx.x;
    float p = bq[tt0 + lane] * bk[tt0 + lane];
    for (int off = 32; off >= 1; off >>= 1) p += __shfl_down(p, off);
    if (lane == 0) atomicAdd(t4, p);
  }
}

__global__ __launch_bounds__(256) void k_cvec(const float* __restrict__ Wo,
                                              const float* __restrict__ bv,
                                              const float* __restrict__ bo,
                                              float* __restrict__ cv) {
  int row = blockIdx.x * 4 + (threadIdx.x >> 6);
  int lane = threadIdx.x & 63;
  float s = 0.f;
  for (int j = lane; j < EE; j += 64) s += Wo[(long)row * EE + j] * bv[j];
  for (int off = 32; off >= 1; off >>= 1) s += __shfl_down(s, off);
  if (lane == 0) cv[row] = s + bo[row];
}

__global__ __launch_bounds__(256) void k_rowterm(const unsigned short* __restrict__ qb,
                                                 const float* __restrict__ u,
                                                 const float* __restrict__ t4,
                                                 float* __restrict__ rt) {
  long row = (long)blockIdx.x * 4 + (threadIdx.x >> 6);
  int lane = threadIdx.x & 63;
  const unsigned short* qr = qb + row * EE;
  float s = 0.f;
#pragma unroll
  for (int it = 0; it < 4; ++it) {
    int e0 = it * 512 + lane * 8;
    ushort8 qv = *(const ushort8*)(qr + e0);
#pragma unroll
    for (int j = 0; j < 8; j++) s += bf2f(qv[j]) * u[e0 + j];
  }
  for (int off = 32; off >= 1; off >>= 1) s += __shfl_down(s, off);
  if (lane == 0) rt[row] = s + *t4;
}

// ---------- 128x128-tile GEMM for the z=2 weight precompute (512 wg) ----------
__global__ __launch_bounds__(512, 4) void k_gemm128(
    const unsigned short* __restrict__ A, long lda, long sA,
    const unsigned short* __restrict__ Bm, long ldb, long sB,
    unsigned short* __restrict__ Co, long ldc, long sC, int K) {
  __shared__ __attribute__((aligned(16))) unsigned short As[2 * 8192];
  __shared__ __attribute__((aligned(16))) unsigned short Bs[2 * 8192];
  const int gx = gridDim.x, gy = gridDim.y;
  int lin = (int)blockIdx.x + gx * ((int)blockIdx.y + gy * (int)blockIdx.z);
  int nwg = gx * gy * (int)gridDim.z;
  int chunk = nwg >> 3;
  int sw = (lin & 7) * chunk + (lin >> 3);
  int bz = sw / (gx * gy); int rem = sw - bz * (gx * gy);
  int by = rem / gx; int bx = rem - by * gx;

  const long m0 = (long)by * 128;
  const long n0 = (long)bx * 128;
  const unsigned short* Ab = A + (long)bz * sA;
  const unsigned short* Bb = Bm + (long)bz * sB;
  const int t = threadIdx.x;
  const int lane = t & 63;
  const int w = t >> 6;
  const int wm = w >> 2, wn = w & 3;

  const int srow = t >> 3;
  const int scol = (((t & 7) * 16) ^ (((t >> 5) & 1) << 5)) >> 1;
  const unsigned short* Ga = Ab + (m0 + srow) * lda + scol;
  const unsigned short* Gb = Bb + (n0 + srow) * ldb + scol;
  const int ldst = t * 8;

#define STAGE(buf, tile) do { \
    const unsigned short* ga_ = Ga + (long)(tile) * 64; \
    const unsigned short* gb_ = Gb + (long)(tile) * 64; \
    unsigned short* la_ = As + (buf) * 8192 + ldst; \
    unsigned short* lb_ = Bs + (buf) * 8192 + ldst; \
    gload16(ga_, la_); gload16(ga_ + 64 * lda, la_ + 4096); \
    gload16(gb_, lb_); gload16(gb_ + 64 * ldb, lb_ + 4096); \
  } while (0)

  const int r = lane & 15;
  const int q = lane >> 4;
  const int rb2 = ((r * 128 + q * 16) ^ ((r & 4) << 3)) >> 1;
  const int aBase = wm * 4096 + rb2;
  const int bBase = wn * 2048 + rb2;

  f32x4 acc[4][2] = {};
  bf16x8 a[4][2], b[2][2];
  const int J = K >> 6;
  STAGE(0, 0);
  WAIT_VM(0);
  BARRIER();
  for (int j = 0; j < J; ++j) {
    const int c = j & 1;
    const unsigned short* Ac = As + c * 8192;
    const unsigned short* Bc = Bs + c * 8192;
#pragma unroll
    for (int mi = 0; mi < 4; mi++)
#pragma unroll
      for (int kk = 0; kk < 2; kk++)
        a[mi][kk] = *(const bf16x8*)(Ac + aBase + mi * 1024 + kk * 32);
#pragma unroll
    for (int ni = 0; ni < 2; ni++)
#pragma unroll
      for (int kk = 0; kk < 2; kk++)
        b[ni][kk] = *(const bf16x8*)(Bc + bBase + ni * 1024 + kk * 32);
    if (j + 1 < J) STAGE(c ^ 1, j + 1);
    __builtin_amdgcn_s_setprio(1);
#pragma unroll
    for (int mi = 0; mi < 4; mi++)
#pragma unroll
      for (int ni = 0; ni < 2; ni++)
#pragma unroll
        for (int kk = 0; kk < 2; kk++)
          acc[mi][ni] = __builtin_amdgcn_mfma_f32_16x16x32_bf16(
              a[mi][kk], b[ni][kk], acc[mi][ni], 0, 0, 0);
    __builtin_amdgcn_s_setprio(0);
    WAIT_VM(0);
    BARRIER();
  }
#undef STAGE
  const int cr0 = wm * 64 + (q << 2);
  const int cc0 = wn * 32 + r;
#pragma unroll
  for (int mi = 0; mi < 4; mi++)
#pragma unroll
    for (int rr = 0; rr < 4; rr++) {
      long row = m0 + cr0 + mi * 16 + rr;
#pragma unroll
      for (int ni = 0; ni < 2; ni++)
        Co[(long)bz * sC + row * ldc + n0 + cc0 + ni * 16] = f2bf(acc[mi][ni][rr]);
    }
}

// ---------- 256x256 8-wave 8-phase GEMM, 16x16x32 MFMA (measured-best) ----------
// EPI 0: bf16 out (+bias[col])
// EPI 1: scores: sm=(acc+rt)*scale+mask*(-1e9); store bf16 compact; edge-dot from
//        fp32 sm via r-lane shfl reduce + LDS(reused SH) + global atomicAdd(edot)
// EPI 2: f32 out + bias[col]
// EPI 3: bf16 TRANSPOSED per-batch write (Vt2T) via swizzled LDS roundtrip:
//        element (row=m0+.., col=n0+..) of [M=B*N, E] -> Cv + (m0/NN)*sC + col*ldc + row%NN
template <int EPI>
__global__ __launch_bounds__(512, 2) void k_gemm256(
    const unsigned short* __restrict__ A, long lda, long sA,
    const unsigned short* __restrict__ Bm, long ldb, long sB,
    void* __restrict__ Cv, long ldc, long sC, int K,
    const float* __restrict__ bias,
    const int* __restrict__ mask, long sMask,
    const float* __restrict__ rt, float scale,
    const float* __restrict__ We, float* __restrict__ edot) {
  __shared__ __attribute__((aligned(16))) unsigned short SH[4 * 16384];  // 128KB
  unsigned short* As = SH;
  unsigned short* Bs = SH + 2 * 16384;

  const int gx = gridDim.x, gy = gridDim.y;
  int lin = (int)blockIdx.x + gx * ((int)blockIdx.y + gy * (int)blockIdx.z);
  int nwg = gx * gy * (int)gridDim.z;
  int chunk = nwg >> 3;
  int sw = (lin & 7) * chunk + (lin >> 3);
  int bz = sw / (gx * gy); int rem = sw - bz * (gx * gy);
  int by = rem / gx; int bx = rem - by * gx;

  const long m0 = (long)by * 256;
  const long n0 = (long)bx * 256;
  const unsigned short* Ab = A + (long)bz * sA;
  const unsigned short* Bb = Bm + (long)bz * sB;

  const int t = threadIdx.x;
  const int lane = t & 63;
  const int w = t >> 6;
  const int wm = w >> 2;
  const int wn = w & 3;

  const int p0 = t * 16;
  const int q0 = p0 ^ (((p0 >> 9) & 1) << 5);
  const int srow = ((q0 >> 10) >> 1) * 16 + ((q0 >> 6) & 15);
  const int scol = ((q0 >> 10) & 1) * 32 + ((q0 & 63) >> 1);
  const unsigned short* Ga = Ab + (m0 + srow) * lda + scol;
  const unsigned short* Gb = Bb + (n0 + srow) * ldb + scol;
  const int ldst = t * 8;

#define STAGE_A(buf, h, tile) do { \
    const unsigned short* g_ = Ga + (long)(tile) * 64 + (long)(h) * 128 * lda; \
    unsigned short* l_ = As + (buf) * 16384 + (h) * 8192 + ldst; \
    gload16(g_, l_); gload16(g_ + 64 * lda, l_ + 4096); \
  } while (0)
#define STAGE_B(buf, h, tile) do { \
    const unsigned short* g_ = Gb + (long)(tile) * 64 + (long)(h) * 128 * ldb; \
    unsigned short* l_ = Bs + (buf) * 16384 + (h) * 8192 + ldst; \
    gload16(g_, l_); gload16(g_ + 64 * ldb, l_ + 4096); \
  } while (0)

  const int r = lane & 15;
  const int q = lane >> 4;
  const int c2h = ((q * 16) ^ (((lane >> 3) & 1) << 5)) >> 1;
  const int aBase = wm * 8192 + r * 32 + c2h;
  const int bBase = (wn >> 1) * 8192 + (wn & 1) * 4096 + r * 32 + c2h;

#define RD_A(bp, mbase) do { \
    _Pragma("unroll") for (int mi = 0; mi < 4; mi++) \
    _Pragma("unroll") for (int kk = 0; kk < 2; kk++) \
      a[mi][kk] = *(const bf16x8*)((bp) + aBase + ((mbase) + mi) * 1024 + kk * 512); \
  } while (0)
#define RD_B(bp, nbase) do { \
    _Pragma("unroll") for (int ni = 0; ni < 2; ni++) \
    _Pragma("unroll") for (int kk = 0; kk < 2; kk++) \
      b[(nbase) + ni][kk] = *(const bf16x8*)((bp) + bBase + ((nbase) + ni) * 1024 + kk * 512); \
  } while (0)
#define MFMA_Q(mbase, nbase) do { \
    BARRIER(); \
    __builtin_amdgcn_s_setprio(1); \
    _Pragma("unroll") for (int mi = 0; mi < 4; mi++) \
    _Pragma("unroll") for (int ni = 0; ni < 2; ni++) \
    _Pragma("unroll") for (int kk = 0; kk < 2; kk++) \
      acc[(mbase) + mi][(nbase) + ni] = __builtin_amdgcn_mfma_f32_16x16x32_bf16( \
          a[mi][kk], b[(nbase) + ni][kk], acc[(mbase) + mi][(nbase) + ni], 0, 0, 0); \
    __builtin_amdgcn_s_setprio(0); \
    BARRIER(); \
  } while (0)

  f32x4 acc[8][4] = {};
  bf16x8 a[4][2], b[4][2];
  const unsigned short* A0 = As;
  const unsigned short* B0 = Bs;
  const unsigned short* A1 = As + 16384;
  const unsigned short* B1 = Bs + 16384;
  const int J = K >> 7;

  STAGE_B(0, 0, 0); STAGE_B(0, 1, 0);
  STAGE_A(0, 0, 0); STAGE_A(0, 1, 0);
  STAGE_B(1, 0, 1); STAGE_B(1, 1, 1);
  WAIT_VM(4);
  BARRIER();

  for (int j = 0; j < J; ++j) {
    const int t0 = 2 * j, t1 = 2 * j + 1;
    const bool pf = (j + 1 < J);

    RD_A(A0, 0); RD_B(B0, 0);
    STAGE_A(1, 0, t1);
    MFMA_Q(0, 0);

    RD_B(B0, 2);
    STAGE_A(1, 1, t1);
    MFMA_Q(0, 2);

    RD_A(A0, 4);
    if (pf) STAGE_B(0, 0, t0 + 2);
    MFMA_Q(4, 0);

    if (pf) { STAGE_B(0, 1, t0 + 2); WAIT_VM(4); } else { WAIT_VM(0); }
    MFMA_Q(4, 2);

    RD_A(A1, 0); RD_B(B1, 0);
    if (pf) STAGE_A(0, 0, t0 + 2);
    MFMA_Q(0, 0);

    RD_B(B1, 2);
    if (pf) STAGE_A(0, 1, t0 + 2);
    MFMA_Q(0, 2);

    RD_A(A1, 4);
    if (pf) STAGE_B(1, 0, t1 + 2);
    MFMA_Q(4, 0);

    if (pf) { STAGE_B(1, 1, t1 + 2); WAIT_VM(4); }
    MFMA_Q(4, 2);
  }
#undef STAGE_A
#undef STAGE_B
#undef RD_A
#undef RD_B
#undef MFMA_Q

  const int cr0 = wm * 128 + (q << 2);
  const int cc0 = wn * 64 + r;
  if (EPI == 0) {
    unsigned short* Co = (unsigned short*)Cv + (long)bz * sC;
#pragma unroll
    for (int mi = 0; mi < 8; mi++)
#pragma unroll
      for (int rr = 0; rr < 4; rr++) {
        long row = m0 + cr0 + mi * 16 + rr;
#pragma unroll
        for (int ni = 0; ni < 4; ni++) {
          long col = n0 + cc0 + ni * 16;
          float v = acc[mi][ni][rr];
          if (bias) v += bias[col];
          Co[row * ldc + col] = f2bf(v);
        }
      }
  } else if (EPI == 1) {
    unsigned short* Co = (unsigned short*)Cv + (long)bz * sC;   // bf16 compact scores
    const int* Mp = mask + (long)bz * sMask;
    const float* rtb = rt + (long)bz * NN;
    float* edpart = (float*)As;   // LDS dead after K-loop (final barrier synced)
    if (t < 256) edpart[t] = 0.f;
    __syncthreads();
    float wec[4];
#pragma unroll
    for (int ni = 0; ni < 4; ni++) wec[ni] = We[n0 + cc0 + ni * 16];
#pragma unroll
    for (int mi = 0; mi < 8; mi++) {
      float pr[4];
#pragma unroll
      for (int rr = 0; rr < 4; rr++) {
        long row = m0 + cr0 + mi * 16 + rr;
        float rv = rtb[row];
        float pv = 0.f;
#pragma unroll
        for (int ni = 0; ni < 4; ni++) {
          long col = n0 + cc0 + ni * 16;
          float sm = (acc[mi][ni][rr] + rv) * scale + (float)Mp[row * ldc + col] * -1e9f;
          Co[row * ldc + col] = f2bf(sm);
          pv += sm * wec[ni];
        }
        pr[rr] = pv;
      }
#pragma unroll
      for (int mask_ = 1; mask_ < 16; mask_ <<= 1)
#pragma unroll
        for (int rr = 0; rr < 4; rr++) pr[rr] += __shfl_xor(pr[rr], mask_);
      if (r == 0) {
#pragma unroll
        for (int rr = 0; rr < 4; rr++)
          atomicAdd(&edpart[cr0 + mi * 16 + rr], pr[rr]);
      }
    }
    __syncthreads();
    if (t < 256) atomicAdd(&edot[(long)bz * NN + m0 + t], edpart[t]);
  } else if (EPI == 2) {
    float* Co = (float*)Cv + (long)bz * sC;
#pragma unroll
    for (int mi = 0; mi < 8; mi++)
#pragma unroll
      for (int rr = 0; rr < 4; rr++) {
        long row = m0 + cr0 + mi * 16 + rr;
#pragma unroll
        for (int ni = 0; ni < 4; ni++) {
          long col = n0 + cc0 + ni * 16;
          Co[row * ldc + col] = acc[mi][ni][rr] + bias[col];
        }
      }
  } else {
    // EPI 3: transposed per-batch bf16 write. LDS (128KB = [256 col][256 row] ushort)
    // phys = colL*256 + (rowL ^ ((colL&15)<<3))  — granule swizzle keeps 8-elem reads
    // contiguous while spreading column-wise scalar writes across banks.
#pragma unroll
    for (int mi = 0; mi < 8; mi++)
#pragma unroll
      for (int rr = 0; rr < 4; rr++) {
        int rowL = cr0 + mi * 16 + rr;
#pragma unroll
        for (int ni = 0; ni < 4; ni++) {
          int colL = cc0 + ni * 16;
          SH[colL * 256 + (rowL ^ ((colL & 15) << 3))] = f2bf(acc[mi][ni][rr]);
        }
      }
    __syncthreads();
    const long zb = m0 / NN;            // tiles never straddle batches (NN%256==0)
    const long lm0 = m0 - zb * NN;
    unsigned short* Co = (unsigned short*)Cv + zb * sC;
    const int er = t >> 1;              // e-index within tile: 0..255
    const int nh = (t & 1) * 128;       // n-half
    const int xr = (er & 15) << 3;
#pragma unroll
    for (int i = 0; i < 16; i++) {
      int n = nh + i * 8;
      ushort8 v = *(const ushort8*)(SH + er * 256 + (n ^ xr));
      *(ushort8*)(Co + (n0 + er) * ldc + lm0 + n) = v;
    }
  }
}

// ---------- edge gate + softmax on compact bf16 scores, in place ----------
__global__ __launch_bounds__(256) void k_edge_softmax(unsigned short* __restrict__ attn,
                                                      const float* __restrict__ edot,
                                                      const float* __restrict__ be) {
  __shared__ float r2[4], r3[4];
  const long row = blockIdx.x;
  unsigned short* srow = attn + row * (long)NN;
  const int t = threadIdx.x;
  const int lane = t & 63;
  const int w = t >> 6;

  float edge = 1.0f / (1.0f + expf(-(edot[row] + be[0])));
  ushort8 v = *(const ushort8*)(srow + t * 8);
  float s[8];
  float mx = -3.4e38f;
#pragma unroll
  for (int j = 0; j < 8; j++) { s[j] = bf2f(v[j]) * edge; mx = fmaxf(mx, s[j]); }
#pragma unroll
  for (int off = 32; off >= 1; off >>= 1) mx = fmaxf(mx, __shfl_down(mx, off));
  if (lane == 0) r2[w] = mx;
  __syncthreads();
  mx = fmaxf(fmaxf(r2[0], r2[1]), fmaxf(r2[2], r2[3]));

  float sum = 0.f;
  float p[8];
#pragma unroll
  for (int j = 0; j < 8; j++) { p[j] = expf(s[j] - mx); sum += p[j]; }
#pragma unroll
  for (int off = 32; off >= 1; off >>= 1) sum += __shfl_down(sum, off);
  if (lane == 0) r3[w] = sum;
  __syncthreads();
  sum = r3[0] + r3[1] + r3[2] + r3[3];
  float inv = 1.0f / sum;

  ushort8 o;
#pragma unroll
  for (int j = 0; j < 8; j++) o[j] = f2bf(p[j] * inv);
  *(ushort8*)(srow + t * 8) = o;
}

// ---------- launch ----------
extern "C" void kernel_launch(void* const* d_in, const int* in_sizes, int n_in,
                              void* d_out, int out_size, void* d_ws, size_t ws_size,
                              hipStream_t stream) {
  (void)in_sizes; (void)n_in; (void)out_size; (void)ws_size;
  const float* query = (const float*)d_in[0];
  const float* key_  = (const float*)d_in[1];
  const float* value = (const float*)d_in[2];
  const int*   mask  = (const int*)d_in[3];
  const float* Wq = (const float*)d_in[4];
  const float* bq = (const float*)d_in[5];
  const float* Wk = (const float*)d_in[6];
  const float* bk = (const float*)d_in[7];
  const float* Wv = (const float*)d_in[8];
  const float* bv = (const float*)d_in[9];
  const float* We = (const float*)d_in[10];
  const float* be = (const float*)d_in[11];
  const float* Wo = (const float*)d_in[12];
  const float* bo = (const float*)d_in[13];
  float* out = (float*)d_out;

  const long WSZ = (long)EE * EE;
  char* ws = (char*)d_ws;
  unsigned short* WkT = (unsigned short*)(ws);
  unsigned short* Wob = WkT + WSZ;
  unsigned short* WqT = WkT + 2 * WSZ;
  unsigned short* WvT = WkT + 3 * WSZ;
  unsigned short* W2T = (unsigned short*)(ws + 33554432L);
  unsigned short* W3T = W2T + WSZ;
  unsigned short* attn = (unsigned short*)(ws);
  unsigned short* qb  = (unsigned short*)(ws + 79691776L);
  unsigned short* kb  = (unsigned short*)(ws + 114294784L);
  unsigned short* vb  = (unsigned short*)(ws + 148897792L);
  unsigned short* Tb  = vb;
  unsigned short* Vt2T = (unsigned short*)(ws + 183500800L);  // written DIRECTLY transposed
  float* cvec = (float*)(ws + 219938816L);
  float* uvec = cvec + EE;
  float* w2b  = cvec + 2 * EE;
  float* t4   = cvec + 3 * EE;
  float* rt   = cvec + 3 * EE + 64;
  float* edot = rt + (long)BB * NN;

  const float scale = 1.0f / sqrtf((float)EE);
  dim3 blk(256), blk5(512);

  // weights: fused fp32->bf16 transposed (Wk,Wq,Wv in ONE dispatch); Wo plain convert
  k_trf2b3<<<dim3(32, 32, 3), blk, 0, stream>>>(Wk, Wq, Wv, WkT, WqT, WvT);
  k_f32_to_bf16<<<2048, blk, 0, stream>>>(Wo, Wob);
  // bias vectors
  hipMemsetAsync(uvec, 0, (2 * EE + 64) * sizeof(float), stream);
  hipMemsetAsync(edot, 0, (long)BB * NN * sizeof(float), stream);
  k_vecw<<<dim3(8, 32), blk, 0, stream>>>(Wq, Wk, bq, bk, uvec, w2b, t4);
  k_cvec<<<512, blk, 0, stream>>>(Wo, bv, bo, cvec);
  // fused weight GEMMs z=2: z0: W2T = WkT.WqT^T;  z1: W3T = Wob.WvT^T
  k_gemm128<<<dim3(16, 16, 2), blk5, 0, stream>>>(WkT, EE, WSZ, WqT, EE, WSZ,
      W2T, EE, WSZ, EE);
  // data -> bf16 (q,k,v in ONE dispatch)
  k_conv3<<<dim3(8192, 1, 3), blk, 0, stream>>>(query, key_, value, qb, kb, vb);
  // Vt2T = transpose_batch(v @ W3) — written directly from the GEMM epilogue (EPI 3)
  k_gemm256<3><<<dim3(8, 32, 1), blk5, 0, stream>>>(vb, EE, 0, W3T, EE, 0,
      Vt2T, NN, (long)EE * NN, EE, nullptr, nullptr, 0, nullptr, 0.f, nullptr, nullptr);
  // T = q @ W2 + w2b  -> Tb (vb region dead after Vt2T GEMM)
  k_gemm256<0><<<dim3(8, 32, 1), blk5, 0, stream>>>(qb, EE, 0, W2T, EE, 0,
      Tb, EE, 0, EE, w2b, nullptr, 0, nullptr, 0.f, nullptr, nullptr);
  // rowterm (reads qb; qb is never overwritten in this schedule)
  k_rowterm<<<2048, blk, 0, stream>>>(qb, uvec, t4, rt);
  // scores -> compact bf16 attn + edge-dot accumulation (fp32)
  k_gemm256<1><<<dim3(8, 8, BB), blk5, 0, stream>>>(Tb, EE, (long)NN * EE, kb, EE, (long)NN * EE,
      attn, NN, (long)NN * NN, EE, nullptr, mask, (long)NN * NN, rt, scale, We, edot);
  // edge gate + softmax in place (compact bf16)
  k_edge_softmax<<<BB * NN, blk, 0, stream>>>(attn, edot, be);
  // out = attn @ Vt2 + cvec
  k_gemm256<2><<<dim3(8, 8, BB), blk5, 0, stream>>>(attn, NN, (long)NN * NN,
      Vt2T, NN, (long)EE * NN, out, EE, (long)NN * EE, NN,
      cvec, nullptr, 0, nullptr, 0.f, nullptr, nullptr);
}

// Round 16
// 420.680 us; speedup vs baseline: 1.5488x; 1.0185x over previous
//
#include <hip/hip_runtime.h>
#include <math.h>

#define BB 4
#define NN 2048
#define EE 2048

typedef __attribute__((ext_vector_type(8))) unsigned short ushort8;
typedef __attribute__((ext_vector_type(8))) __bf16 bf16x8;
typedef __attribute__((ext_vector_type(4))) float f32x4;

// ---------- helpers ----------
__device__ __forceinline__ unsigned short f2bf(float f) {
  unsigned int u = __float_as_uint(f);
  u = u + 0x7fffu + ((u >> 16) & 1u);   // RNE; inputs are finite
  return (unsigned short)(u >> 16);
}
__device__ __forceinline__ float bf2f(unsigned short h) {
  return __uint_as_float((unsigned)h << 16);
}

__device__ __forceinline__ void gload16(const void* g, void* l) {
  __builtin_amdgcn_global_load_lds(
      (__attribute__((address_space(1))) void*)g,
      (__attribute__((address_space(3))) void*)l, 16, 0, 0);
}

#define BARRIER() __builtin_amdgcn_s_barrier()
#define WAIT_VM(N) asm volatile("s_waitcnt vmcnt(" #N ")")

// ---------- fp32 -> bf16 conversion (vectorized) ----------
__global__ __launch_bounds__(256) void k_f32_to_bf16(const float* __restrict__ in,
                                                     unsigned short* __restrict__ out) {
  size_t i = (size_t)blockIdx.x * 256 + threadIdx.x;   // 8 elems each
  const float4* ip = (const float4*)in;
  float4 a = ip[i * 2];
  float4 b = ip[i * 2 + 1];
  ushort8 o;
  o[0] = f2bf(a.x); o[1] = f2bf(a.y); o[2] = f2bf(a.z); o[3] = f2bf(a.w);
  o[4] = f2bf(b.x); o[5] = f2bf(b.y); o[6] = f2bf(b.z); o[7] = f2bf(b.w);
  *((ushort8*)out + i) = o;
}

// ---------- fused q/k/v conversion, one dispatch (z selects tensor) ----------
__global__ __launch_bounds__(256) void k_conv3(const float* __restrict__ s0,
                                               const float* __restrict__ s1,
                                               const float* __restrict__ s2,
                                               unsigned short* __restrict__ d0,
                                               unsigned short* __restrict__ d1,
                                               unsigned short* __restrict__ d2) {
  const float* in; unsigned short* out;
  if (blockIdx.z == 0) { in = s0; out = d0; }
  else if (blockIdx.z == 1) { in = s1; out = d1; }
  else { in = s2; out = d2; }
  size_t i = (size_t)blockIdx.x * 256 + threadIdx.x;
  const float4* ip = (const float4*)in;
  float4 a = ip[i * 2];
  float4 b = ip[i * 2 + 1];
  ushort8 o;
  o[0] = f2bf(a.x); o[1] = f2bf(a.y); o[2] = f2bf(a.z); o[3] = f2bf(a.w);
  o[4] = f2bf(b.x); o[5] = f2bf(b.y); o[6] = f2bf(b.z); o[7] = f2bf(b.w);
  *((ushort8*)out + i) = o;
}

// ---------- fused fp32 read -> bf16 transposed write, 3 weights in one dispatch ----------
__global__ __launch_bounds__(256) void k_trf2b3(const float* __restrict__ s0,
                                                const float* __restrict__ s1,
                                                const float* __restrict__ s2,
                                                unsigned short* __restrict__ d0,
                                                unsigned short* __restrict__ d1,
                                                unsigned short* __restrict__ d2) {
  __shared__ __attribute__((aligned(16))) unsigned short tile[64][72];
  const float* in; unsigned short* out;
  if (blockIdx.z == 0) { in = s0; out = d0; }
  else if (blockIdx.z == 1) { in = s1; out = d1; }
  else { in = s2; out = d2; }
  const long eb = (long)blockIdx.x * 64;
  const long nb = (long)blockIdx.y * 64;
  const int t = threadIdx.x;
  const int r = t >> 3;
  const int c = (t & 7) * 8;

  const float* p0 = in + (nb + r) * (long)EE + eb + c;
  const float* p1 = in + (nb + 32 + r) * (long)EE + eb + c;
  float4 a0 = *(const float4*)p0, a1 = *(const float4*)(p0 + 4);
  float4 b0 = *(const float4*)p1, b1 = *(const float4*)(p1 + 4);
  unsigned short* t0 = &tile[r][c];
  unsigned short* t1 = &tile[r + 32][c];
  t0[0] = f2bf(a0.x); t0[1] = f2bf(a0.y); t0[2] = f2bf(a0.z); t0[3] = f2bf(a0.w);
  t0[4] = f2bf(a1.x); t0[5] = f2bf(a1.y); t0[6] = f2bf(a1.z); t0[7] = f2bf(a1.w);
  t1[0] = f2bf(b0.x); t1[1] = f2bf(b0.y); t1[2] = f2bf(b0.z); t1[3] = f2bf(b0.w);
  t1[4] = f2bf(b1.x); t1[5] = f2bf(b1.y); t1[6] = f2bf(b1.z); t1[7] = f2bf(b1.w);
  __syncthreads();
  ushort8 o0, o1;
#pragma unroll
  for (int j = 0; j < 8; j++) { o0[j] = tile[c + j][r]; o1[j] = tile[c + j][r + 32]; }
  *(ushort8*)(out + (eb + r) * (long)NN + nb + c) = o0;
  *(ushort8*)(out + (eb + r + 32) * (long)NN + nb + c) = o1;
}

// ---------- fused bias precompute: blocks [0,256) = vecw, [256,768) = cvec ----------
// u[e]=sum_t Wq[t,e]*bk[t]; w2b[e]=sum_t Wk[t,e]*bq[t]; *t4=bq.bk (atomic-accumulated)
// cv[i]=bo[i]+sum_j Wo[i,j]*bv[j]
__global__ __launch_bounds__(256) void k_bias(const float* __restrict__ Wq,
                                              const float* __restrict__ Wk,
                                              const float* __restrict__ Wo,
                                              const float* __restrict__ bq,
                                              const float* __restrict__ bk,
                                              const float* __restrict__ bv,
                                              const float* __restrict__ bo,
                                              float* __restrict__ u,
                                              float* __restrict__ w2b,
                                              float* __restrict__ t4,
                                              float* __restrict__ cv) {
  const int bxx = blockIdx.x;
  if (bxx < 256) {
    const int e = (bxx & 7) * 256 + threadIdx.x;
    const int tt0 = (bxx >> 3) * 64;
    float su = 0.f, sw = 0.f;
#pragma unroll 4
    for (int i = 0; i < 64; i++) {
      int tt = tt0 + i;
      su += Wq[(long)tt * EE + e] * bk[tt];
      sw += Wk[(long)tt * EE + e] * bq[tt];
    }
    atomicAdd(&u[e], su);
    atomicAdd(&w2b[e], sw);
    if ((bxx & 7) == 0 && threadIdx.x < 64) {
      int lane = threadIdx.x;
      float p = bq[tt0 + lane] * bk[tt0 + lane];
      for (int off = 32; off >= 1; off >>= 1) p += __shfl_down(p, off);
      if (lane == 0) atomicAdd(t4, p);
    }
  } else {
    int row = (bxx - 256) * 4 + (threadIdx.x >> 6);
    int lane = threadIdx.x & 63;
    float s = 0.f;
    for (int j = lane; j < EE; j += 64) s += Wo[(long)row * EE + j] * bv[j];
    for (int off = 32; off >= 1; off >>= 1) s += __shfl_down(s, off);
    if (lane == 0) cv[row] = s + bo[row];
  }
}

__global__ __launch_bounds__(256) void k_rowterm(const unsigned short* __restrict__ qb,
                                                 const float* __restrict__ u,
                                                 const float* __restrict__ t4,
                                                 float* __restrict__ rt) {
  long row = (long)blockIdx.x * 4 + (threadIdx.x >> 6);
  int lane = threadIdx.x & 63;
  const unsigned short* qr = qb + row * EE;
  float s = 0.f;
#pragma unroll
  for (int it = 0; it < 4; ++it) {
    int e0 = it * 512 + lane * 8;
    ushort8 qv = *(const ushort8*)(qr + e0);
#pragma unroll
    for (int j = 0; j < 8; j++) s += bf2f(qv[j]) * u[e0 + j];
  }
  for (int off = 32; off >= 1; off >>= 1) s += __shfl_down(s, off);
  if (lane == 0) rt[row] = s + *t4;
}

// ---------- 128x128-tile GEMM for the z=2 weight precompute (512 wg, merged-SH) ----------
__global__ __launch_bounds__(512, 4) void k_gemm128(
    const unsigned short* __restrict__ A, long lda, long sA,
    const unsigned short* __restrict__ Bm, long ldb, long sB,
    unsigned short* __restrict__ Co, long ldc, long sC, int K) {
  __shared__ __attribute__((aligned(16))) unsigned short SH[4 * 8192];  // 64KB
  unsigned short* As = SH;
  unsigned short* Bs = SH + 2 * 8192;
  const int gx = gridDim.x, gy = gridDim.y;
  int lin = (int)blockIdx.x + gx * ((int)blockIdx.y + gy * (int)blockIdx.z);
  int nwg = gx * gy * (int)gridDim.z;
  int chunk = nwg >> 3;
  int sw = (lin & 7) * chunk + (lin >> 3);
  int bz = sw / (gx * gy); int rem = sw - bz * (gx * gy);
  int by = rem / gx; int bx = rem - by * gx;

  const long m0 = (long)by * 128;
  const long n0 = (long)bx * 128;
  const unsigned short* Ab = A + (long)bz * sA;
  const unsigned short* Bb = Bm + (long)bz * sB;
  const int t = threadIdx.x;
  const int lane = t & 63;
  const int w = t >> 6;
  const int wm = w >> 2, wn = w & 3;

  const int srow = t >> 3;
  const int scol = (((t & 7) * 16) ^ (((t >> 5) & 1) << 5)) >> 1;
  const unsigned short* Ga = Ab + (m0 + srow) * lda + scol;
  const unsigned short* Gb = Bb + (n0 + srow) * ldb + scol;
  const int ldst = t * 8;

#define STAGE(buf, tile) do { \
    const unsigned short* ga_ = Ga + (long)(tile) * 64; \
    const unsigned short* gb_ = Gb + (long)(tile) * 64; \
    unsigned short* la_ = As + (buf) * 8192 + ldst; \
    unsigned short* lb_ = Bs + (buf) * 8192 + ldst; \
    gload16(ga_, la_); gload16(ga_ + 64 * lda, la_ + 4096); \
    gload16(gb_, lb_); gload16(gb_ + 64 * ldb, lb_ + 4096); \
  } while (0)

  const int r = lane & 15;
  const int q = lane >> 4;
  const int rb2 = ((r * 128 + q * 16) ^ ((r & 4) << 3)) >> 1;
  const int aBase = wm * 4096 + rb2;
  const int bBase = wn * 2048 + rb2;

  f32x4 acc[4][2] = {};
  bf16x8 a[4][2], b[2][2];
  const int J = K >> 6;
  STAGE(0, 0);
  WAIT_VM(0);
  BARRIER();
  for (int j = 0; j < J; ++j) {
    const int c = j & 1;
    const unsigned short* Ac = As + c * 8192;
    const unsigned short* Bc = Bs + c * 8192;
#pragma unroll
    for (int mi = 0; mi < 4; mi++)
#pragma unroll
      for (int kk = 0; kk < 2; kk++)
        a[mi][kk] = *(const bf16x8*)(Ac + aBase + mi * 1024 + kk * 32);
#pragma unroll
    for (int ni = 0; ni < 2; ni++)
#pragma unroll
      for (int kk = 0; kk < 2; kk++)
        b[ni][kk] = *(const bf16x8*)(Bc + bBase + ni * 1024 + kk * 32);
    if (j + 1 < J) STAGE(c ^ 1, j + 1);
    __builtin_amdgcn_s_setprio(1);
#pragma unroll
    for (int mi = 0; mi < 4; mi++)
#pragma unroll
      for (int ni = 0; ni < 2; ni++)
#pragma unroll
        for (int kk = 0; kk < 2; kk++)
          acc[mi][ni] = __builtin_amdgcn_mfma_f32_16x16x32_bf16(
              a[mi][kk], b[ni][kk], acc[mi][ni], 0, 0, 0);
    __builtin_amdgcn_s_setprio(0);
    WAIT_VM(0);
    BARRIER();
  }
#undef STAGE
  const int cr0 = wm * 64 + (q << 2);
  const int cc0 = wn * 32 + r;
#pragma unroll
  for (int mi = 0; mi < 4; mi++)
#pragma unroll
    for (int rr = 0; rr < 4; rr++) {
      long row = m0 + cr0 + mi * 16 + rr;
#pragma unroll
      for (int ni = 0; ni < 2; ni++)
        Co[(long)bz * sC + row * ldc + n0 + cc0 + ni * 16] = f2bf(acc[mi][ni][rr]);
    }
}

// ---------- 256x256 8-wave 8-phase GEMM, 16x16x32 MFMA (measured-best, merged-SH) ----------
// EPI 0: bf16 out (+bias[col])
// EPI 1: scores: sm=(acc+rt)*scale+mask*(-1e9); store bf16 compact; edge-dot from
//        fp32 sm via r-lane shfl reduce + LDS(reused SH) + global atomicAdd(edot)
// EPI 2: f32 out + bias[col]
// EPI 3: bf16 TRANSPOSED per-batch write (Vt2T) via swizzled LDS roundtrip
template <int EPI>
__global__ __launch_bounds__(512, 2) void k_gemm256(
    const unsigned short* __restrict__ A, long lda, long sA,
    const unsigned short* __restrict__ Bm, long ldb, long sB,
    void* __restrict__ Cv, long ldc, long sC, int K,
    const float* __restrict__ bias,
    const int* __restrict__ mask, long sMask,
    const float* __restrict__ rt, float scale,
    const float* __restrict__ We, float* __restrict__ edot) {
  __shared__ __attribute__((aligned(16))) unsigned short SH[4 * 16384];  // 128KB
  unsigned short* As = SH;
  unsigned short* Bs = SH + 2 * 16384;

  const int gx = gridDim.x, gy = gridDim.y;
  int lin = (int)blockIdx.x + gx * ((int)blockIdx.y + gy * (int)blockIdx.z);
  int nwg = gx * gy * (int)gridDim.z;
  int chunk = nwg >> 3;
  int sw = (lin & 7) * chunk + (lin >> 3);
  int bz = sw / (gx * gy); int rem = sw - bz * (gx * gy);
  int by = rem / gx; int bx = rem - by * gx;

  const long m0 = (long)by * 256;
  const long n0 = (long)bx * 256;
  const unsigned short* Ab = A + (long)bz * sA;
  const unsigned short* Bb = Bm + (long)bz * sB;

  const int t = threadIdx.x;
  const int lane = t & 63;
  const int w = t >> 6;
  const int wm = w >> 2;
  const int wn = w & 3;

  const int p0 = t * 16;
  const int q0 = p0 ^ (((p0 >> 9) & 1) << 5);
  const int srow = ((q0 >> 10) >> 1) * 16 + ((q0 >> 6) & 15);
  const int scol = ((q0 >> 10) & 1) * 32 + ((q0 & 63) >> 1);
  const unsigned short* Ga = Ab + (m0 + srow) * lda + scol;
  const unsigned short* Gb = Bb + (n0 + srow) * ldb + scol;
  const int ldst = t * 8;

#define STAGE_A(buf, h, tile) do { \
    const unsigned short* g_ = Ga + (long)(tile) * 64 + (long)(h) * 128 * lda; \
    unsigned short* l_ = As + (buf) * 16384 + (h) * 8192 + ldst; \
    gload16(g_, l_); gload16(g_ + 64 * lda, l_ + 4096); \
  } while (0)
#define STAGE_B(buf, h, tile) do { \
    const unsigned short* g_ = Gb + (long)(tile) * 64 + (long)(h) * 128 * ldb; \
    unsigned short* l_ = Bs + (buf) * 16384 + (h) * 8192 + ldst; \
    gload16(g_, l_); gload16(g_ + 64 * ldb, l_ + 4096); \
  } while (0)

  const int r = lane & 15;
  const int q = lane >> 4;
  const int c2h = ((q * 16) ^ (((lane >> 3) & 1) << 5)) >> 1;
  const int aBase = wm * 8192 + r * 32 + c2h;
  const int bBase = (wn >> 1) * 8192 + (wn & 1) * 4096 + r * 32 + c2h;

#define RD_A(bp, mbase) do { \
    _Pragma("unroll") for (int mi = 0; mi < 4; mi++) \
    _Pragma("unroll") for (int kk = 0; kk < 2; kk++) \
      a[mi][kk] = *(const bf16x8*)((bp) + aBase + ((mbase) + mi) * 1024 + kk * 512); \
  } while (0)
#define RD_B(bp, nbase) do { \
    _Pragma("unroll") for (int ni = 0; ni < 2; ni++) \
    _Pragma("unroll") for (int kk = 0; kk < 2; kk++) \
      b[(nbase) + ni][kk] = *(const bf16x8*)((bp) + bBase + ((nbase) + ni) * 1024 + kk * 512); \
  } while (0)
#define MFMA_Q(mbase, nbase) do { \
    BARRIER(); \
    __builtin_amdgcn_s_setprio(1); \
    _Pragma("unroll") for (int mi = 0; mi < 4; mi++) \
    _Pragma("unroll") for (int ni = 0; ni < 2; ni++) \
    _Pragma("unroll") for (int kk = 0; kk < 2; kk++) \
      acc[(mbase) + mi][(nbase) + ni] = __builtin_amdgcn_mfma_f32_16x16x32_bf16( \
          a[mi][kk], b[(nbase) + ni][kk], acc[(mbase) + mi][(nbase) + ni], 0, 0, 0); \
    __builtin_amdgcn_s_setprio(0); \
    BARRIER(); \
  } while (0)

  f32x4 acc[8][4] = {};
  bf16x8 a[4][2], b[4][2];
  const unsigned short* A0 = As;
  const unsigned short* B0 = Bs;
  const unsigned short* A1 = As + 16384;
  const unsigned short* B1 = Bs + 16384;
  const int J = K >> 7;

  STAGE_B(0, 0, 0); STAGE_B(0, 1, 0);
  STAGE_A(0, 0, 0); STAGE_A(0, 1, 0);
  STAGE_B(1, 0, 1); STAGE_B(1, 1, 1);
  WAIT_VM(4);
  BARRIER();

  for (int j = 0; j < J; ++j) {
    const int t0 = 2 * j, t1 = 2 * j + 1;
    const bool pf = (j + 1 < J);

    RD_A(A0, 0); RD_B(B0, 0);
    STAGE_A(1, 0, t1);
    MFMA_Q(0, 0);

    RD_B(B0, 2);
    STAGE_A(1, 1, t1);
    MFMA_Q(0, 2);

    RD_A(A0, 4);
    if (pf) STAGE_B(0, 0, t0 + 2);
    MFMA_Q(4, 0);

    if (pf) { STAGE_B(0, 1, t0 + 2); WAIT_VM(4); } else { WAIT_VM(0); }
    MFMA_Q(4, 2);

    RD_A(A1, 0); RD_B(B1, 0);
    if (pf) STAGE_A(0, 0, t0 + 2);
    MFMA_Q(0, 0);

    RD_B(B1, 2);
    if (pf) STAGE_A(0, 1, t0 + 2);
    MFMA_Q(0, 2);

    RD_A(A1, 4);
    if (pf) STAGE_B(1, 0, t1 + 2);
    MFMA_Q(4, 0);

    if (pf) { STAGE_B(1, 1, t1 + 2); WAIT_VM(4); }
    MFMA_Q(4, 2);
  }
#undef STAGE_A
#undef STAGE_B
#undef RD_A
#undef RD_B
#undef MFMA_Q

  const int cr0 = wm * 128 + (q << 2);
  const int cc0 = wn * 64 + r;
  if (EPI == 0) {
    unsigned short* Co = (unsigned short*)Cv + (long)bz * sC;
#pragma unroll
    for (int mi = 0; mi < 8; mi++)
#pragma unroll
      for (int rr = 0; rr < 4; rr++) {
        long row = m0 + cr0 + mi * 16 + rr;
#pragma unroll
        for (int ni = 0; ni < 4; ni++) {
          long col = n0 + cc0 + ni * 16;
          float v = acc[mi][ni][rr];
          if (bias) v += bias[col];
          Co[row * ldc + col] = f2bf(v);
        }
      }
  } else if (EPI == 1) {
    unsigned short* Co = (unsigned short*)Cv + (long)bz * sC;   // bf16 compact scores
    const int* Mp = mask + (long)bz * sMask;
    const float* rtb = rt + (long)bz * NN;
    float* edpart = (float*)As;   // LDS dead after K-loop (final barrier synced)
    if (t < 256) edpart[t] = 0.f;
    __syncthreads();
    float wec[4];
#pragma unroll
    for (int ni = 0; ni < 4; ni++) wec[ni] = We[n0 + cc0 + ni * 16];
#pragma unroll
    for (int mi = 0; mi < 8; mi++) {
      float pr[4];
#pragma unroll
      for (int rr = 0; rr < 4; rr++) {
        long row = m0 + cr0 + mi * 16 + rr;
        float rv = rtb[row];
        float pv = 0.f;
#pragma unroll
        for (int ni = 0; ni < 4; ni++) {
          long col = n0 + cc0 + ni * 16;
          float sm = (acc[mi][ni][rr] + rv) * scale + (float)Mp[row * ldc + col] * -1e9f;
          Co[row * ldc + col] = f2bf(sm);
          pv += sm * wec[ni];
        }
        pr[rr] = pv;
      }
#pragma unroll
      for (int mask_ = 1; mask_ < 16; mask_ <<= 1)
#pragma unroll
        for (int rr = 0; rr < 4; rr++) pr[rr] += __shfl_xor(pr[rr], mask_);
      if (r == 0) {
#pragma unroll
        for (int rr = 0; rr < 4; rr++)
          atomicAdd(&edpart[cr0 + mi * 16 + rr], pr[rr]);
      }
    }
    __syncthreads();
    if (t < 256) atomicAdd(&edot[(long)bz * NN + m0 + t], edpart[t]);
  } else if (EPI == 2) {
    float* Co = (float*)Cv + (long)bz * sC;
#pragma unroll
    for (int mi = 0; mi < 8; mi++)
#pragma unroll
      for (int rr = 0; rr < 4; rr++) {
        long row = m0 + cr0 + mi * 16 + rr;
#pragma unroll
        for (int ni = 0; ni < 4; ni++) {
          long col = n0 + cc0 + ni * 16;
          Co[row * ldc + col] = acc[mi][ni][rr] + bias[col];
        }
      }
  } else {
    // EPI 3: transposed per-batch bf16 write (swizzled LDS roundtrip)
#pragma unroll
    for (int mi = 0; mi < 8; mi++)
#pragma unroll
      for (int rr = 0; rr < 4; rr++) {
        int rowL = cr0 + mi * 16 + rr;
#pragma unroll
        for (int ni = 0; ni < 4; ni++) {
          int colL = cc0 + ni * 16;
          SH[colL * 256 + (rowL ^ ((colL & 15) << 3))] = f2bf(acc[mi][ni][rr]);
        }
      }
    __syncthreads();
    const long zb = m0 / NN;            // tiles never straddle batches (NN%256==0)
    const long lm0 = m0 - zb * NN;
    unsigned short* Co = (unsigned short*)Cv + zb * sC;
    const int er = t >> 1;              // e-index within tile: 0..255
    const int nh = (t & 1) * 128;       // n-half
    const int xr = (er & 15) << 3;
#pragma unroll
    for (int i = 0; i < 16; i++) {
      int n = nh + i * 8;
      ushort8 v = *(const ushort8*)(SH + er * 256 + (n ^ xr));
      *(ushort8*)(Co + (n0 + er) * ldc + lm0 + n) = v;
    }
  }
}

// ---------- edge gate + softmax on compact bf16 scores, in place ----------
__global__ __launch_bounds__(256) void k_edge_softmax(unsigned short* __restrict__ attn,
                                                      const float* __restrict__ edot,
                                                      const float* __restrict__ be) {
  __shared__ float r2[4], r3[4];
  const long row = blockIdx.x;
  unsigned short* srow = attn + row * (long)NN;
  const int t = threadIdx.x;
  const int lane = t & 63;
  const int w = t >> 6;

  float edge = 1.0f / (1.0f + expf(-(edot[row] + be[0])));
  ushort8 v = *(const ushort8*)(srow + t * 8);
  float s[8];
  float mx = -3.4e38f;
#pragma unroll
  for (int j = 0; j < 8; j++) { s[j] = bf2f(v[j]) * edge; mx = fmaxf(mx, s[j]); }
#pragma unroll
  for (int off = 32; off >= 1; off >>= 1) mx = fmaxf(mx, __shfl_down(mx, off));
  if (lane == 0) r2[w] = mx;
  __syncthreads();
  mx = fmaxf(fmaxf(r2[0], r2[1]), fmaxf(r2[2], r2[3]));

  float sum = 0.f;
  float p[8];
#pragma unroll
  for (int j = 0; j < 8; j++) { p[j] = expf(s[j] - mx); sum += p[j]; }
#pragma unroll
  for (int off = 32; off >= 1; off >>= 1) sum += __shfl_down(sum, off);
  if (lane == 0) r3[w] = sum;
  __syncthreads();
  sum = r3[0] + r3[1] + r3[2] + r3[3];
  float inv = 1.0f / sum;

  ushort8 o;
#pragma unroll
  for (int j = 0; j < 8; j++) o[j] = f2bf(p[j] * inv);
  *(ushort8*)(srow + t * 8) = o;
}

// ---------- launch ----------
extern "C" void kernel_launch(void* const* d_in, const int* in_sizes, int n_in,
                              void* d_out, int out_size, void* d_ws, size_t ws_size,
                              hipStream_t stream) {
  (void)in_sizes; (void)n_in; (void)out_size; (void)ws_size;
  const float* query = (const float*)d_in[0];
  const float* key_  = (const float*)d_in[1];
  const float* value = (const float*)d_in[2];
  const int*   mask  = (const int*)d_in[3];
  const float* Wq = (const float*)d_in[4];
  const float* bq = (const float*)d_in[5];
  const float* Wk = (const float*)d_in[6];
  const float* bk = (const float*)d_in[7];
  const float* Wv = (const float*)d_in[8];
  const float* bv = (const float*)d_in[9];
  const float* We = (const float*)d_in[10];
  const float* be = (const float*)d_in[11];
  const float* Wo = (const float*)d_in[12];
  const float* bo = (const float*)d_in[13];
  float* out = (float*)d_out;

  const long WSZ = (long)EE * EE;
  char* ws = (char*)d_ws;
  unsigned short* WkT = (unsigned short*)(ws);
  unsigned short* Wob = WkT + WSZ;
  unsigned short* WqT = WkT + 2 * WSZ;
  unsigned short* WvT = WkT + 3 * WSZ;
  unsigned short* W2T = (unsigned short*)(ws + 33554432L);
  unsigned short* W3T = W2T + WSZ;
  unsigned short* attn = (unsigned short*)(ws);
  unsigned short* qb  = (unsigned short*)(ws + 79691776L);
  unsigned short* kb  = (unsigned short*)(ws + 114294784L);
  unsigned short* vb  = (unsigned short*)(ws + 148897792L);
  unsigned short* Tb  = vb;
  unsigned short* Vt2T = (unsigned short*)(ws + 183500800L);  // written DIRECTLY transposed
  float* cvec = (float*)(ws + 219938816L);
  float* uvec = cvec + EE;
  float* w2b  = cvec + 2 * EE;
  float* t4   = cvec + 3 * EE;
  float* rt   = cvec + 3 * EE + 64;
  float* edot = rt + (long)BB * NN;

  const float scale = 1.0f / sqrtf((float)EE);
  dim3 blk(256), blk5(512);

  // weights: fused fp32->bf16 transposed (Wk,Wq,Wv in ONE dispatch); Wo plain convert
  k_trf2b3<<<dim3(32, 32, 3), blk, 0, stream>>>(Wk, Wq, Wv, WkT, WqT, WvT);
  k_f32_to_bf16<<<2048, blk, 0, stream>>>(Wo, Wob);
  // bias vectors (fused vecw+cvec, zero-initialized accumulators)
  hipMemsetAsync(uvec, 0, (2 * EE + 64) * sizeof(float), stream);
  hipMemsetAsync(edot, 0, (long)BB * NN * sizeof(float), stream);
  k_bias<<<768, blk, 0, stream>>>(Wq, Wk, Wo, bq, bk, bv, bo, uvec, w2b, t4, cvec);
  // fused weight GEMMs z=2: z0: W2T = WkT.WqT^T;  z1: W3T = Wob.WvT^T
  k_gemm128<<<dim3(16, 16, 2), blk5, 0, stream>>>(WkT, EE, WSZ, WqT, EE, WSZ,
      W2T, EE, WSZ, EE);
  // data -> bf16 (q,k,v in ONE dispatch)
  k_conv3<<<dim3(8192, 1, 3), blk, 0, stream>>>(query, key_, value, qb, kb, vb);
  // Vt2T = transpose_batch(v @ W3) — written directly from the GEMM epilogue (EPI 3)
  k_gemm256<3><<<dim3(8, 32, 1), blk5, 0, stream>>>(vb, EE, 0, W3T, EE, 0,
      Vt2T, NN, (long)EE * NN, EE, nullptr, nullptr, 0, nullptr, 0.f, nullptr, nullptr);
  // T = q @ W2 + w2b  -> Tb (vb region dead after Vt2T GEMM)
  k_gemm256<0><<<dim3(8, 32, 1), blk5, 0, stream>>>(qb, EE, 0, W2T, EE, 0,
      Tb, EE, 0, EE, w2b, nullptr, 0, nullptr, 0.f, nullptr, nullptr);
  // rowterm (reads qb; qb is never overwritten in this schedule)
  k_rowterm<<<2048, blk, 0, stream>>>(qb, uvec, t4, rt);
  // scores -> compact bf16 attn + edge-dot accumulation (fp32)
  k_gemm256<1><<<dim3(8, 8, BB), blk5, 0, stream>>>(Tb, EE, (long)NN * EE, kb, EE, (long)NN * EE,
      attn, NN, (long)NN * NN, EE, nullptr, mask, (long)NN * NN, rt, scale, We, edot);
  // edge gate + softmax in place (compact bf16)
  k_edge_softmax<<<BB * NN, blk, 0, stream>>>(attn, edot, be);
  // out = attn @ Vt2 + cvec
  k_gemm256<2><<<dim3(8, 8, BB), blk5, 0, stream>>>(attn, NN, (long)NN * NN,
      Vt2T, NN, (long)EE * NN, out, EE, (long)NN * EE, NN,
      cvec, nullptr, 0, nullptr, 0.f, nullptr, nullptr);
}